// Round 6
// baseline (277.836 us; speedup 1.0000x reference)
//
#include <hip/hip_runtime.h>

#define Bb 8
#define Cc 256
#define C4 64
#define Nn 4096

typedef _Float16 half8 __attribute__((ext_vector_type(8)));
typedef float f32x4 __attribute__((ext_vector_type(4)));
typedef unsigned int u32;

__device__ __forceinline__ f32x4 fz4() {
  f32x4 z; z[0] = 0.f; z[1] = 0.f; z[2] = 0.f; z[3] = 0.f; return z;
}
__device__ __forceinline__ f32x4 mfma16(half8 a, half8 b, f32x4 c) {
  return __builtin_amdgcn_mfma_f32_16x16x32_f16(a, b, c, 0, 0, 0);
}
__device__ __forceinline__ u32 pkrtz(float a, float b) {
  typedef __fp16 h2n __attribute__((ext_vector_type(2)));
  h2n h = __builtin_amdgcn_cvt_pkrtz(a, b);
  return __builtin_bit_cast(u32, h);
}
#define BAR_LGKM()                                          \
  asm volatile("s_waitcnt lgkmcnt(0)" ::: "memory");        \
  __builtin_amdgcn_s_barrier()

// ---------------- K0: weight prep (f16; hi/lo split only for w_qk) ----------------
__global__ void k0_weights(const float* __restrict__ wqk, const float* __restrict__ wv,
                           const float* __restrict__ wt,
                           _Float16* __restrict__ wqkh, _Float16* __restrict__ wqkl,
                           _Float16* __restrict__ wvf, _Float16* __restrict__ wtf) {
  int idx = blockIdx.x * 256 + threadIdx.x;
  if (idx < C4 * Cc) {
    float f = wqk[idx];
    _Float16 h = (_Float16)f;
    wqkh[idx] = h;
    wqkl[idx] = (_Float16)(f - (float)h);
  }
  if (idx < Cc * Cc) {
    wvf[idx] = (_Float16)wv[idx];
    wtf[idx] = (_Float16)wt[idx];
  }
}

// ---------------- K23: qk (f16, computed with hi/lo split) + x_v ----------------
// qkf: [b][n][64] f16   xvf: [b][c][n] f16
__global__ __launch_bounds__(512) void k23_qkv(
    const float* __restrict__ x,
    const _Float16* __restrict__ wqkh, const _Float16* __restrict__ wqkl,
    const _Float16* __restrict__ wvf, const float* __restrict__ bv,
    _Float16* __restrict__ qkf, _Float16* __restrict__ xvf) {
  __shared__ _Float16 xh[64 * 264];  // [n][c] transposed x, hi
  __shared__ _Float16 xl[64 * 264];  // lo
  const int bid = blockIdx.x;
  const int b = bid & 7, n0 = (bid >> 3) * 64, tid = threadIdx.x;
  {
    const int cc = tid >> 3, nn = (tid & 7) * 8;
    #pragma unroll
    for (int ph = 0; ph < 4; ++ph) {
      int c = cc + ph * 64;
      const float* src = x + ((size_t)(b * Cc + c)) * Nn + n0 + nn;
      float4 v0 = *(const float4*)(src);
      float4 v1 = *(const float4*)(src + 4);
      float vv[8] = {v0.x, v0.y, v0.z, v0.w, v1.x, v1.y, v1.z, v1.w};
      #pragma unroll
      for (int j = 0; j < 8; ++j) {
        _Float16 h = (_Float16)vv[j];
        xh[(nn + j) * 264 + c] = h;
        xl[(nn + j) * 264 + c] = (_Float16)(vv[j] - (float)h);
      }
    }
  }
  __syncthreads();
  const int w = tid >> 6, lane = tid & 63, l15 = lane & 15, l4 = lane >> 4;
  // ---- q: out [64 n][64 o], K=256, 3-term f16 split ----
  {
    const int fn = w >> 1, ob = (w & 1) * 32;
    f32x4 acc[2] = {fz4(), fz4()};
    #pragma unroll
    for (int kb = 0; kb < 8; ++kb) {
      const int k = kb * 32 + l4 * 8;
      half8 ah = *(const half8*)(xh + (fn * 16 + l15) * 264 + k);
      half8 al = *(const half8*)(xl + (fn * 16 + l15) * 264 + k);
      #pragma unroll
      for (int f = 0; f < 2; ++f) {
        const int o = ob + f * 16 + l15;
        half8 bh = *(const half8*)(wqkh + o * Cc + k);
        half8 bl = *(const half8*)(wqkl + o * Cc + k);
        acc[f] = mfma16(ah, bh, acc[f]);
        acc[f] = mfma16(ah, bl, acc[f]);
        acc[f] = mfma16(al, bh, acc[f]);
      }
    }
    #pragma unroll
    for (int f = 0; f < 2; ++f)
      #pragma unroll
      for (int i = 0; i < 4; ++i) {
        const int n = n0 + fn * 16 + l4 * 4 + i;
        const int o = ob + f * 16 + l15;
        qkf[((size_t)b * Nn + n) * C4 + o] = (_Float16)acc[f][i];
      }
  }
  // ---- x_v: out [256 c][64 n], K=256, single f16 ----
  {
    const int cb = w * 32;
    f32x4 acc[2][4];
    #pragma unroll
    for (int a = 0; a < 2; ++a)
      #pragma unroll
      for (int q = 0; q < 4; ++q) acc[a][q] = fz4();
    #pragma unroll
    for (int kb = 0; kb < 8; ++kb) {
      const int k = kb * 32 + l4 * 8;
      half8 bfr[4];
      #pragma unroll
      for (int fnb = 0; fnb < 4; ++fnb)
        bfr[fnb] = *(const half8*)(xh + (fnb * 16 + l15) * 264 + k);
      #pragma unroll
      for (int fc = 0; fc < 2; ++fc) {
        const int c = cb + fc * 16 + l15;
        half8 a = *(const half8*)(wvf + c * Cc + k);
        #pragma unroll
        for (int fnb = 0; fnb < 4; ++fnb)
          acc[fc][fnb] = mfma16(a, bfr[fnb], acc[fc][fnb]);
      }
    }
    #pragma unroll
    for (int fc = 0; fc < 2; ++fc)
      #pragma unroll
      for (int fnb = 0; fnb < 4; ++fnb)
        #pragma unroll
        for (int i = 0; i < 4; ++i) {
          const int c = cb + fc * 16 + l4 * 4 + i;
          const int n = n0 + fnb * 16 + l15;
          xvf[((size_t)b * Cc + c) * Nn + n] = (_Float16)(acc[fc][fnb][i] + bv[c]);
        }
  }
}

// ---------------- K4: softmax row stats  a_n = 64 + log(sum_m exp(E-64)) ----------------
// Zero in-loop LDS, zero in-loop barriers. qn stationary in regs; qm A-frags reg-direct
// from L2 (batch-per-XCD). Unique-m wave mapping: wave w owns m-rows it*128 + w*16 + l15.
__global__ __launch_bounds__(512, 4) void k4_stats(
    const _Float16* __restrict__ qkf, float* __restrict__ stats) {
  __shared__ float red[64][8];
  const int bid = blockIdx.x;
  const int b = bid & 7, n0 = (bid >> 3) * 64, tid = threadIdx.x;
  const int w = tid >> 6, lane = tid & 63, l15 = lane & 15, l4 = lane >> 4;
  const size_t bq = (size_t)b * Nn;

  // stationary qn (B operand rows n = n0 + fn*16 + l15)
  half8 qn_r[2][4];
  #pragma unroll
  for (int kb = 0; kb < 2; ++kb)
    #pragma unroll
    for (int fn = 0; fn < 4; ++fn)
      qn_r[kb][fn] = *(const half8*)(qkf + (bq + n0 + fn * 16 + l15) * C4 + kb * 32 + l4 * 8);

  // qm A-frags, single-buffered (reloaded after use each iter)
  half8 qa0, qa1;
  {
    const _Float16* qr = qkf + (bq + (size_t)w * 16 + l15) * C4 + l4 * 8;
    qa0 = *(const half8*)qr;
    qa1 = *(const half8*)(qr + 32);
  }

  float sm[4] = {0.f, 0.f, 0.f, 0.f};
  for (int it = 0; it < 32; ++it) {
    f32x4 g[4] = {fz4(), fz4(), fz4(), fz4()};
    #pragma unroll
    for (int fn = 0; fn < 4; ++fn) g[fn] = mfma16(qa0, qn_r[0][fn], g[fn]);
    #pragma unroll
    for (int fn = 0; fn < 4; ++fn) g[fn] = mfma16(qa1, qn_r[1][fn], g[fn]);
    // reload qm for next iter (WAR: issued after MFMAs read qa)
    const int itn = it + (it < 31);
    const _Float16* qr = qkf + (bq + (size_t)itn * 128 + w * 16 + l15) * C4 + l4 * 8;
    qa0 = *(const half8*)qr;
    qa1 = *(const half8*)(qr + 32);
    #pragma unroll
    for (int fn = 0; fn < 4; ++fn)
      #pragma unroll
      for (int i = 0; i < 4; ++i)
        sm[fn] += __expf(g[fn][i] - 64.0f);
  }
  #pragma unroll
  for (int fn = 0; fn < 4; ++fn) {
    sm[fn] += __shfl_xor(sm[fn], 16, 64);
    sm[fn] += __shfl_xor(sm[fn], 32, 64);
  }
  if (l4 == 0) {
    #pragma unroll
    for (int fn = 0; fn < 4; ++fn) red[fn * 16 + l15][w] = sm[fn];
  }
  __syncthreads();
  if (tid < 64) {
    float t = 0.f;
    #pragma unroll
    for (int j = 0; j < 8; ++j) t += red[tid][j];
    stats[bq + n0 + tid] = 64.0f + __logf(t);
  }
}

// ---------------- K5: fused attention-apply + conv_t + BN + ReLU + residual ----------------
// Only P crosses waves -> only PT in LDS (double-buffered, 1 barrier/iter).
// qn/xv/an reg-direct from L2 (batch-per-XCD), single-buffer prefetch after last use.
// G waves: (wa m32, wb n16). PV waves: w owns unique c32 slice, full m64.
__global__ __launch_bounds__(512, 4) void k5_main(
    const float* __restrict__ x,
    const _Float16* __restrict__ qkf, const _Float16* __restrict__ xvf,
    const float* __restrict__ stats,
    const _Float16* __restrict__ wtf, const float* __restrict__ bt,
    const float* __restrict__ gamma, const float* __restrict__ beta,
    const float* __restrict__ rmean, const float* __restrict__ rvar,
    float* __restrict__ out) {
  __shared__ __align__(16) char smem[34048];  // loop: PT dbuf 2x8K; epilogue: st[64][264] f16
  const int bid = blockIdx.x;
  const int b = bid & 7, m0 = (bid >> 3) * 64, tid = threadIdx.x;
  const int w = tid >> 6, lane = tid & 63, l15 = lane & 15, l4 = lane >> 4;
  const int wa = w >> 2;  // G: m 32-block
  const int wb = w & 3;   // G: n 16-block
  const size_t bq = (size_t)b * Nn;
  const _Float16* xvbb = xvf + (size_t)b * Cc * Nn;
  const int key = l15 & 7;

  // stationary qm (G B-operand rows m = m0 + wa*32 + fm*16 + l15)
  half8 qm_r[2][2];
  #pragma unroll
  for (int kb = 0; kb < 2; ++kb)
    #pragma unroll
    for (int fm = 0; fm < 2; ++fm)
      qm_r[kb][fm] = *(const half8*)(qkf + (bq + m0 + wa * 32 + fm * 16 + l15) * C4 +
                                     kb * 32 + l4 * 8);

  // single-buffered prefetch state
  half8 qa0, qa1;          // qn A-frags (rows n = it*64 + wb*16 + l15)
  half8 xb[2][2];          // xv B-frags [fc][kb], c = w*32 + fc*16 + l15
  float4 an;               // stats for current it
  {
    const _Float16* qr = qkf + (bq + (size_t)wb * 16 + l15) * C4 + l4 * 8;
    qa0 = *(const half8*)qr;
    qa1 = *(const half8*)(qr + 32);
    #pragma unroll
    for (int fc = 0; fc < 2; ++fc)
      #pragma unroll
      for (int kb = 0; kb < 2; ++kb)
        xb[fc][kb] = *(const half8*)(xvbb + (size_t)(w * 32 + fc * 16 + l15) * Nn +
                                     kb * 32 + l4 * 8);
    an = *(const float4*)(stats + bq + wb * 16 + l4 * 4);
  }

  f32x4 acc[4][2];  // [fm m16][fc c16]
  #pragma unroll
  for (int a = 0; a < 4; ++a)
    #pragma unroll
    for (int q = 0; q < 2; ++q) acc[a][q] = fz4();

  for (int it = 0; it < 64; ++it) {
    const int itn = it + (it < 63);
    char* PTp = smem + ((it & 1) << 13);
    // ---- G: P rows m (wa*32+fm*16+l15), cols n (wb*16+l4*4+i) ----
    f32x4 g0 = fz4(), g1 = fz4();
    g0 = mfma16(qa0, qm_r[0][0], g0);
    g1 = mfma16(qa0, qm_r[0][1], g1);
    g0 = mfma16(qa1, qm_r[1][0], g0);
    g1 = mfma16(qa1, qm_r[1][1], g1);
    // reload qn for it+1 (WAR after G reads)
    {
      const _Float16* qr = qkf + (bq + (size_t)itn * 64 + wb * 16 + l15) * C4 + l4 * 8;
      qa0 = *(const half8*)qr;
      qa1 = *(const half8*)(qr + 32);
    }
    // ---- exp + packed PT write (swizzled) ----
    {
      uint2 pk;
      pk.x = pkrtz(__expf(g0[0] - an.x), __expf(g0[1] - an.y));
      pk.y = pkrtz(__expf(g0[2] - an.z), __expf(g0[3] - an.w));
      *(uint2*)(PTp + (wa * 32 + l15) * 128 + ((wb * 32 + l4 * 8) ^ (key << 4))) = pk;
      pk.x = pkrtz(__expf(g1[0] - an.x), __expf(g1[1] - an.y));
      pk.y = pkrtz(__expf(g1[2] - an.z), __expf(g1[3] - an.w));
      *(uint2*)(PTp + (wa * 32 + 16 + l15) * 128 + ((wb * 32 + l4 * 8) ^ (key << 4))) = pk;
    }
    // reload an for it+1 (WAR after exp)
    an = *(const float4*)(stats + bq + (size_t)itn * 64 + wb * 16 + l4 * 4);
    BAR_LGKM();  // PT[p] visible to all; only barrier of the iteration
    // ---- PV: x_r^T[m][c] += P[m][n] * xv[c][n]; wave owns c32, m64 ----
    __builtin_amdgcn_s_setprio(1);
    #pragma unroll
    for (int kb = 0; kb < 2; ++kb) {
      half8 pa[4];
      #pragma unroll
      for (int fm = 0; fm < 4; ++fm)
        pa[fm] = *(const half8*)(PTp + (fm * 16 + l15) * 128 + (((kb * 4 + l4) ^ key) * 16));
      #pragma unroll
      for (int fm = 0; fm < 4; ++fm)
        #pragma unroll
        for (int fc = 0; fc < 2; ++fc)
          acc[fm][fc] = mfma16(pa[fm], xb[fc][kb], acc[fm][fc]);
    }
    __builtin_amdgcn_s_setprio(0);
    // reload xv for it+1 (WAR after PV reads)
    #pragma unroll
    for (int fc = 0; fc < 2; ++fc)
      #pragma unroll
      for (int kb = 0; kb < 2; ++kb)
        xb[fc][kb] = *(const half8*)(xvbb + (size_t)(w * 32 + fc * 16 + l15) * Nn +
                                     (size_t)itn * 64 + kb * 32 + l4 * 8);
  }
  BAR_LGKM();  // all PV reads drained before smem reuse

  // ---- Epilogue: s^T = x - x_r^T into st[64][264] f16 ----
  _Float16* st = (_Float16*)smem;
  #pragma unroll
  for (int fm = 0; fm < 4; ++fm)
    #pragma unroll
    for (int fc = 0; fc < 2; ++fc) {
      int c = w * 32 + fc * 16 + l15;
      const float* xp = x + ((size_t)b * Cc + c) * Nn + m0 + fm * 16 + l4 * 4;
      float4 v = *(const float4*)xp;
      float vv[4] = {v.x, v.y, v.z, v.w};
      #pragma unroll
      for (int i = 0; i < 4; ++i) {
        int m = fm * 16 + l4 * 4 + i;
        st[m * 264 + c] = (_Float16)(vv[i] - acc[fm][fc][i]);
      }
    }
  __syncthreads();
  // ---- t = w_t . s + b_t, BN, ReLU, +x ----
  {
    const int ob = (w >> 1) * 64, mb2 = (w & 1) * 32;
    f32x4 t[4][2];
    #pragma unroll
    for (int a = 0; a < 4; ++a)
      #pragma unroll
      for (int q = 0; q < 2; ++q) t[a][q] = fz4();
    #pragma unroll
    for (int kb = 0; kb < 8; ++kb) {
      const int k = kb * 32 + l4 * 8;
      half8 bfr[2];
      #pragma unroll
      for (int fm2 = 0; fm2 < 2; ++fm2)
        bfr[fm2] = *(const half8*)(st + (mb2 + fm2 * 16 + l15) * 264 + k);
      #pragma unroll
      for (int fo = 0; fo < 4; ++fo) {
        half8 a = *(const half8*)(wtf + (ob + fo * 16 + l15) * Cc + k);
        #pragma unroll
        for (int fm2 = 0; fm2 < 2; ++fm2)
          t[fo][fm2] = mfma16(a, bfr[fm2], t[fo][fm2]);
      }
    }
    #pragma unroll
    for (int fo = 0; fo < 4; ++fo)
      #pragma unroll
      for (int i = 0; i < 4; ++i) {
        const int o = ob + fo * 16 + l4 * 4 + i;
        const float inv = gamma[o] * rsqrtf(rvar[o] + 1e-5f);
        const float addv = beta[o] - rmean[o] * inv;
        const float btv = bt[o];
        #pragma unroll
        for (int fm2 = 0; fm2 < 2; ++fm2) {
          const int m = m0 + mb2 + fm2 * 16 + l15;
          float tv = t[fo][fm2][i] + btv;
          float bn = tv * inv + addv;
          float xr = x[((size_t)b * Cc + o) * Nn + m];
          out[((size_t)b * Cc + o) * Nn + m] = xr + fmaxf(bn, 0.0f);
        }
      }
  }
}

extern "C" void kernel_launch(void* const* d_in, const int* in_sizes, int n_in,
                              void* d_out, int out_size, void* d_ws, size_t ws_size,
                              hipStream_t stream) {
  const float* x = (const float*)d_in[0];
  const float* wqk = (const float*)d_in[1];
  const float* wv = (const float*)d_in[2];
  const float* bv = (const float*)d_in[3];
  const float* wt = (const float*)d_in[4];
  const float* bt = (const float*)d_in[5];
  const float* gamma = (const float*)d_in[6];
  const float* beta = (const float*)d_in[7];
  const float* rmean = (const float*)d_in[8];
  const float* rvar = (const float*)d_in[9];
  float* out = (float*)d_out;

  char* ws = (char*)d_ws;
  size_t off = 0;
  auto alloc = [&](size_t nb) {
    char* p = ws + off;
    off += (nb + 255) & ~(size_t)255;
    return p;
  };
  _Float16* qkf = (_Float16*)alloc((size_t)Bb * Nn * C4 * 2);
  _Float16* xvf = (_Float16*)alloc((size_t)Bb * Cc * Nn * 2);
  float* stats = (float*)alloc((size_t)Bb * Nn * 4);
  _Float16* wqkh = (_Float16*)alloc((size_t)C4 * Cc * 2);
  _Float16* wqkl = (_Float16*)alloc((size_t)C4 * Cc * 2);
  _Float16* wvf = (_Float16*)alloc((size_t)Cc * Cc * 2);
  _Float16* wtf = (_Float16*)alloc((size_t)Cc * Cc * 2);

  k0_weights<<<dim3(256), dim3(256), 0, stream>>>(wqk, wv, wt, wqkh, wqkl, wvf, wtf);
  k23_qkv<<<dim3(512), dim3(512), 0, stream>>>(x, wqkh, wqkl, wvf, bv, qkf, xvf);
  k4_stats<<<dim3(512), dim3(512), 0, stream>>>(qkf, stats);
  k5_main<<<dim3(512), dim3(512), 0, stream>>>(x, qkf, xvf, stats, wtf, bt,
                                               gamma, beta, rmean, rvar, out);
}

// Round 7
// 190.989 us; speedup vs baseline: 1.4547x; 1.4547x over previous
//
#include <hip/hip_runtime.h>

#define Bb 8
#define Cc 256
#define C4 64
#define Nn 4096

typedef _Float16 half8 __attribute__((ext_vector_type(8)));
typedef float f32x4 __attribute__((ext_vector_type(4)));
typedef unsigned int u32;

__device__ __forceinline__ f32x4 fz4() {
  f32x4 z; z[0] = 0.f; z[1] = 0.f; z[2] = 0.f; z[3] = 0.f; return z;
}
__device__ __forceinline__ f32x4 mfma16(half8 a, half8 b, f32x4 c) {
  return __builtin_amdgcn_mfma_f32_16x16x32_f16(a, b, c, 0, 0, 0);
}
__device__ __forceinline__ u32 pkrtz(float a, float b) {
  typedef __fp16 h2n __attribute__((ext_vector_type(2)));
  h2n h = __builtin_amdgcn_cvt_pkrtz(a, b);
  return __builtin_bit_cast(u32, h);
}
__device__ __forceinline__ void gll16(const void* g, void* l) {
  __builtin_amdgcn_global_load_lds(
      (const __attribute__((address_space(1))) u32*)g,
      (__attribute__((address_space(3))) u32*)l, 16, 0, 0);
}

// ---------------- K0: weight prep (f16; hi/lo split for w_qk, scaled to log2 domain) ----
__global__ void k0_weights(const float* __restrict__ wqk, const float* __restrict__ wv,
                           const float* __restrict__ wt,
                           _Float16* __restrict__ wqkh, _Float16* __restrict__ wqkl,
                           _Float16* __restrict__ wvf, _Float16* __restrict__ wtf) {
  int idx = blockIdx.x * 256 + threadIdx.x;
  if (idx < C4 * Cc) {
    float f = wqk[idx] * 1.2011224087864498f;  // 1/sqrt(ln2): E' = E/ln2
    _Float16 h = (_Float16)f;
    wqkh[idx] = h;
    wqkl[idx] = (_Float16)(f - (float)h);
  }
  if (idx < Cc * Cc) {
    wvf[idx] = (_Float16)wv[idx];
    wtf[idx] = (_Float16)wt[idx];
  }
}

// ---------------- K23: qk (f16, hi/lo split compute) + x_v ----------------
// qkf: [b][n][64] f16 (log2-scaled)   xvf: [b][c][n] f16
__global__ __launch_bounds__(512) void k23_qkv(
    const float* __restrict__ x,
    const _Float16* __restrict__ wqkh, const _Float16* __restrict__ wqkl,
    const _Float16* __restrict__ wvf, const float* __restrict__ bv,
    _Float16* __restrict__ qkf, _Float16* __restrict__ xvf) {
  __shared__ _Float16 xh[64 * 264];
  __shared__ _Float16 xl[64 * 264];
  const int bid = blockIdx.x;
  const int b = bid & 7, n0 = (bid >> 3) * 64, tid = threadIdx.x;
  {
    const int cc = tid >> 3, nn = (tid & 7) * 8;
    #pragma unroll
    for (int ph = 0; ph < 4; ++ph) {
      int c = cc + ph * 64;
      const float* src = x + ((size_t)(b * Cc + c)) * Nn + n0 + nn;
      float4 v0 = *(const float4*)(src);
      float4 v1 = *(const float4*)(src + 4);
      float vv[8] = {v0.x, v0.y, v0.z, v0.w, v1.x, v1.y, v1.z, v1.w};
      #pragma unroll
      for (int j = 0; j < 8; ++j) {
        _Float16 h = (_Float16)vv[j];
        xh[(nn + j) * 264 + c] = h;
        xl[(nn + j) * 264 + c] = (_Float16)(vv[j] - (float)h);
      }
    }
  }
  __syncthreads();
  const int w = tid >> 6, lane = tid & 63, l15 = lane & 15, l4 = lane >> 4;
  {
    const int fn = w >> 1, ob = (w & 1) * 32;
    f32x4 acc[2] = {fz4(), fz4()};
    #pragma unroll
    for (int kb = 0; kb < 8; ++kb) {
      const int k = kb * 32 + l4 * 8;
      half8 ah = *(const half8*)(xh + (fn * 16 + l15) * 264 + k);
      half8 al = *(const half8*)(xl + (fn * 16 + l15) * 264 + k);
      #pragma unroll
      for (int f = 0; f < 2; ++f) {
        const int o = ob + f * 16 + l15;
        half8 bh = *(const half8*)(wqkh + o * Cc + k);
        half8 bl = *(const half8*)(wqkl + o * Cc + k);
        acc[f] = mfma16(ah, bh, acc[f]);
        acc[f] = mfma16(ah, bl, acc[f]);
        acc[f] = mfma16(al, bh, acc[f]);
      }
    }
    #pragma unroll
    for (int f = 0; f < 2; ++f)
      #pragma unroll
      for (int i = 0; i < 4; ++i) {
        const int n = n0 + fn * 16 + l4 * 4 + i;
        const int o = ob + f * 16 + l15;
        qkf[((size_t)b * Nn + n) * C4 + o] = (_Float16)acc[f][i];
      }
  }
  {
    const int cb = w * 32;
    f32x4 acc[2][4];
    #pragma unroll
    for (int a = 0; a < 2; ++a)
      #pragma unroll
      for (int q = 0; q < 4; ++q) acc[a][q] = fz4();
    #pragma unroll
    for (int kb = 0; kb < 8; ++kb) {
      const int k = kb * 32 + l4 * 8;
      half8 bfr[4];
      #pragma unroll
      for (int fnb = 0; fnb < 4; ++fnb)
        bfr[fnb] = *(const half8*)(xh + (fnb * 16 + l15) * 264 + k);
      #pragma unroll
      for (int fc = 0; fc < 2; ++fc) {
        const int c = cb + fc * 16 + l15;
        half8 a = *(const half8*)(wvf + c * Cc + k);
        #pragma unroll
        for (int fnb = 0; fnb < 4; ++fnb)
          acc[fc][fnb] = mfma16(a, bfr[fnb], acc[fc][fnb]);
      }
    }
    #pragma unroll
    for (int fc = 0; fc < 2; ++fc)
      #pragma unroll
      for (int fnb = 0; fnb < 4; ++fnb)
        #pragma unroll
        for (int i = 0; i < 4; ++i) {
          const int c = cb + fc * 16 + l4 * 4 + i;
          const int n = n0 + fnb * 16 + l15;
          xvf[((size_t)b * Cc + c) * Nn + n] = (_Float16)(acc[fc][fnb][i] + bv[c]);
        }
  }
}

// ---------------- K4: softmax row stats  a'_n = 32 + log2(sum_m 2^(E'-32)) ----------------
// Zero in-loop LDS/barriers (validated round 6). exp2-domain.
__global__ __launch_bounds__(512, 4) void k4_stats(
    const _Float16* __restrict__ qkf, float* __restrict__ stats) {
  __shared__ float red[64][8];
  const int bid = blockIdx.x;
  const int b = bid & 7, n0 = (bid >> 3) * 64, tid = threadIdx.x;
  const int w = tid >> 6, lane = tid & 63, l15 = lane & 15, l4 = lane >> 4;
  const size_t bq = (size_t)b * Nn;

  half8 qn_r[2][4];
  #pragma unroll
  for (int kb = 0; kb < 2; ++kb)
    #pragma unroll
    for (int fn = 0; fn < 4; ++fn)
      qn_r[kb][fn] = *(const half8*)(qkf + (bq + n0 + fn * 16 + l15) * C4 + kb * 32 + l4 * 8);

  half8 qa0, qa1;
  {
    const _Float16* qr = qkf + (bq + (size_t)w * 16 + l15) * C4 + l4 * 8;
    qa0 = *(const half8*)qr;
    qa1 = *(const half8*)(qr + 32);
  }

  float sm[4] = {0.f, 0.f, 0.f, 0.f};
  for (int it = 0; it < 32; ++it) {
    f32x4 g[4] = {fz4(), fz4(), fz4(), fz4()};
    #pragma unroll
    for (int fn = 0; fn < 4; ++fn) g[fn] = mfma16(qa0, qn_r[0][fn], g[fn]);
    #pragma unroll
    for (int fn = 0; fn < 4; ++fn) g[fn] = mfma16(qa1, qn_r[1][fn], g[fn]);
    const int itn = it + (it < 31);
    const _Float16* qr = qkf + (bq + (size_t)itn * 128 + w * 16 + l15) * C4 + l4 * 8;
    qa0 = *(const half8*)qr;
    qa1 = *(const half8*)(qr + 32);
    #pragma unroll
    for (int fn = 0; fn < 4; ++fn)
      #pragma unroll
      for (int i = 0; i < 4; ++i)
        sm[fn] += exp2f(g[fn][i] - 32.0f);
  }
  #pragma unroll
  for (int fn = 0; fn < 4; ++fn) {
    sm[fn] += __shfl_xor(sm[fn], 16, 64);
    sm[fn] += __shfl_xor(sm[fn], 32, 64);
  }
  if (l4 == 0) {
    #pragma unroll
    for (int fn = 0; fn < 4; ++fn) red[fn * 16 + l15][w] = sm[fn];
  }
  __syncthreads();
  if (tid < 64) {
    float t = 0.f;
    #pragma unroll
    for (int j = 0; j < 8; ++j) t += red[tid][j];
    stats[bq + n0 + tid] = 32.0f + log2f(t);
  }
}

// ---------------- K5: fused attention-apply + conv_t + BN + ReLU + residual ----------------
// 1 barrier/iter (counted vmcnt(2)). qn: 3-buf gll, 2-iter lead. PT: dbuf. xv: wave-private
// single-buf gll, guarded by wave-local vmcnt/lgkm. PV wave = m64 x c32 (private xv slice).
__global__ __launch_bounds__(512, 4) void k5_main(
    const float* __restrict__ x,
    const _Float16* __restrict__ qkf, const _Float16* __restrict__ xvf,
    const float* __restrict__ stats,
    const _Float16* __restrict__ wtf, const float* __restrict__ bt,
    const float* __restrict__ gamma, const float* __restrict__ beta,
    const float* __restrict__ rmean, const float* __restrict__ rvar,
    float* __restrict__ out) {
  // [0,24K): qn 3 bufs [64n][64k] swz | [24K,40K): PT dbuf [64m][64n] swz | [40K,72K): xv 8x4K
  __shared__ __align__(16) char smem[73728];
  const int bid = blockIdx.x;
  const int b = bid & 7, m0 = (bid >> 3) * 64, tid = threadIdx.x;
  const int w = tid >> 6, lane = tid & 63, l15 = lane & 15, l4 = lane >> 4;
  const int wa = w >> 2;  // G: m 32-block
  const int wb = w & 3;   // G: n 16-block
  const int lr3 = lane >> 3, lc3 = lane & 7;
  const size_t bq = (size_t)b * Nn;
  const _Float16* xvbb = xvf + (size_t)b * Cc * Nn;
  const int key = l15 & 7;
  char* xvw = smem + 40960 + (w << 12);  // wave-private [c32][n64] swz

  // stationary qm (G B-operand rows m = m0 + wa*32 + fm*16 + l15)
  half8 qm_r[2][2];
  #pragma unroll
  for (int kb = 0; kb < 2; ++kb)
    #pragma unroll
    for (int fm = 0; fm < 2; ++fm)
      qm_r[kb][fm] = *(const half8*)(qkf + (bq + m0 + wa * 32 + fm * 16 + l15) * C4 +
                                     kb * 32 + l4 * 8);

  auto qn_issue = [&](int itx, int buf) {
    gll16(qkf + (bq + (size_t)itx * 64 + (tid >> 3)) * C4 + (lc3 ^ lr3) * 8,
          smem + buf * 8192 + w * 1024);
  };
  auto xv_issue = [&](int itx) {
    #pragma unroll
    for (int j = 0; j < 4; ++j) {
      int c = w * 32 + j * 8 + lr3;
      gll16(xvbb + (size_t)c * Nn + itx * 64 + (lc3 ^ lr3) * 8, xvw + j * 1024);
    }
  };

  f32x4 acc[4][2];  // [fm m16 of m64][fc c16 of c32]
  #pragma unroll
  for (int a = 0; a < 4; ++a)
    #pragma unroll
    for (int q = 0; q < 2; ++q) acc[a][q] = fz4();

  // prologue: qn[0]->buf0, qn[1]->buf1, xv[0]->own region, an[0]
  qn_issue(0, 0);
  qn_issue(1, 1);
  xv_issue(0);
  float4 an = *(const float4*)(stats + bq + wb * 16 + l4 * 4);
  asm volatile("s_waitcnt vmcnt(0) lgkmcnt(0)" ::: "memory");
  __builtin_amdgcn_sched_barrier(0);
  __builtin_amdgcn_s_barrier();

  int br = 0, bw = 2;  // qn read/write buffer indices (mod 3 rotation)
  for (int it = 0; it < 64; ++it) {
    const int itn = it + (it < 63);
    // top: stage qn[it+2] (2-iteration lead)
    {
      int itp = it + 2 < 64 ? it + 2 : 63;
      qn_issue(itp, bw);
      bw = bw == 2 ? 0 : bw + 1;
    }
    // ---- G: rows n (wb*16+l4*4+i), cols m (wa*32+fm*16+l15) ----
    const char* qb = smem + br * 8192;
    br = br == 2 ? 0 : br + 1;
    f32x4 g0 = fz4(), g1 = fz4();
    #pragma unroll
    for (int kb = 0; kb < 2; ++kb) {
      half8 ah = *(const half8*)(qb + (wb * 16 + l15) * 128 + (((kb * 4 + l4) ^ key) * 16));
      g0 = mfma16(ah, qm_r[kb][0], g0);
      g1 = mfma16(ah, qm_r[kb][1], g1);
    }
    // ---- P = 2^(E' - a'_n), packed f16, swizzled PT write ----
    char* PTp = smem + 24576 + ((it & 1) << 13);
    {
      uint2 pk;
      pk.x = pkrtz(exp2f(g0[0] - an.x), exp2f(g0[1] - an.y));
      pk.y = pkrtz(exp2f(g0[2] - an.z), exp2f(g0[3] - an.w));
      *(uint2*)(PTp + (wa * 32 + l15) * 128 + ((wb * 32 + l4 * 8) ^ (key << 4))) = pk;
      pk.x = pkrtz(exp2f(g1[0] - an.x), exp2f(g1[1] - an.y));
      pk.y = pkrtz(exp2f(g1[2] - an.z), exp2f(g1[3] - an.w));
      *(uint2*)(PTp + (wa * 32 + 16 + l15) * 128 + ((wb * 32 + l4 * 8) ^ (key << 4))) = pk;
    }
    // an for it+1 (compiler-managed reg dep)
    an = *(const float4*)(stats + bq + (size_t)itn * 64 + wb * 16 + l4 * 4);
    // ---- single barrier: PT visible; xv[it]+qn[it+1] landed (counted: leave qn[it+2], an) ----
    asm volatile("s_waitcnt vmcnt(2) lgkmcnt(0)" ::: "memory");
    __builtin_amdgcn_sched_barrier(0);
    __builtin_amdgcn_s_barrier();
    // ---- PV: x_r^T[m][c] += P[m][n] * xv[c][n]; wave = m64 x private c32 ----
    __builtin_amdgcn_s_setprio(1);
    #pragma unroll
    for (int kb = 0; kb < 2; ++kb) {
      half8 pa[4], xb[2];
      #pragma unroll
      for (int fm = 0; fm < 4; ++fm)
        pa[fm] = *(const half8*)(PTp + (fm * 16 + l15) * 128 + (((kb * 4 + l4) ^ key) * 16));
      #pragma unroll
      for (int fc = 0; fc < 2; ++fc)
        xb[fc] = *(const half8*)(xvw + (fc * 16 + l15) * 128 + (((kb * 4 + l4) ^ key) * 16));
      #pragma unroll
      for (int fm = 0; fm < 4; ++fm)
        #pragma unroll
        for (int fc = 0; fc < 2; ++fc)
          acc[fm][fc] = mfma16(pa[fm], xb[fc], acc[fm][fc]);
    }
    __builtin_amdgcn_s_setprio(0);
    // re-stage own xv[it+1] (wave-local: own reads retired first)
    asm volatile("s_waitcnt lgkmcnt(0)" ::: "memory");
    __builtin_amdgcn_sched_barrier(0);
    xv_issue(itn);
  }
  asm volatile("s_waitcnt vmcnt(0) lgkmcnt(0)" ::: "memory");
  __builtin_amdgcn_sched_barrier(0);
  __builtin_amdgcn_s_barrier();

  // ---- Epilogue: s^T = x - x_r^T into st[64][264] f16 ----
  _Float16* st = (_Float16*)smem;
  #pragma unroll
  for (int fm = 0; fm < 4; ++fm)
    #pragma unroll
    for (int fc = 0; fc < 2; ++fc) {
      int c = w * 32 + fc * 16 + l15;
      const float* xp = x + ((size_t)b * Cc + c) * Nn + m0 + fm * 16 + l4 * 4;
      float4 v = *(const float4*)xp;
      float vv[4] = {v.x, v.y, v.z, v.w};
      #pragma unroll
      for (int i = 0; i < 4; ++i) {
        int m = fm * 16 + l4 * 4 + i;
        st[m * 264 + c] = (_Float16)(vv[i] - acc[fm][fc][i]);
      }
    }
  __syncthreads();
  // ---- t = w_t . s + b_t, BN, ReLU, +x ----
  {
    const int ob = (w >> 1) * 64, mb2 = (w & 1) * 32;
    f32x4 t[4][2];
    #pragma unroll
    for (int a = 0; a < 4; ++a)
      #pragma unroll
      for (int q = 0; q < 2; ++q) t[a][q] = fz4();
    #pragma unroll
    for (int kb = 0; kb < 8; ++kb) {
      const int k = kb * 32 + l4 * 8;
      half8 bfr[2];
      #pragma unroll
      for (int fm2 = 0; fm2 < 2; ++fm2)
        bfr[fm2] = *(const half8*)(st + (mb2 + fm2 * 16 + l15) * 264 + k);
      #pragma unroll
      for (int fo = 0; fo < 4; ++fo) {
        half8 a = *(const half8*)(wtf + (ob + fo * 16 + l15) * Cc + k);
        #pragma unroll
        for (int fm2 = 0; fm2 < 2; ++fm2)
          t[fo][fm2] = mfma16(a, bfr[fm2], t[fo][fm2]);
      }
    }
    #pragma unroll
    for (int fo = 0; fo < 4; ++fo)
      #pragma unroll
      for (int i = 0; i < 4; ++i) {
        const int o = ob + fo * 16 + l4 * 4 + i;
        const float inv = gamma[o] * rsqrtf(rvar[o] + 1e-5f);
        const float addv = beta[o] - rmean[o] * inv;
        const float btv = bt[o];
        #pragma unroll
        for (int fm2 = 0; fm2 < 2; ++fm2) {
          const int m = m0 + mb2 + fm2 * 16 + l15;
          float tv = t[fo][fm2][i] + btv;
          float bn = tv * inv + addv;
          float xr = x[((size_t)b * Cc + o) * Nn + m];
          out[((size_t)b * Cc + o) * Nn + m] = xr + fmaxf(bn, 0.0f);
        }
      }
  }
}

extern "C" void kernel_launch(void* const* d_in, const int* in_sizes, int n_in,
                              void* d_out, int out_size, void* d_ws, size_t ws_size,
                              hipStream_t stream) {
  const float* x = (const float*)d_in[0];
  const float* wqk = (const float*)d_in[1];
  const float* wv = (const float*)d_in[2];
  const float* bv = (const float*)d_in[3];
  const float* wt = (const float*)d_in[4];
  const float* bt = (const float*)d_in[5];
  const float* gamma = (const float*)d_in[6];
  const float* beta = (const float*)d_in[7];
  const float* rmean = (const float*)d_in[8];
  const float* rvar = (const float*)d_in[9];
  float* out = (float*)d_out;

  char* ws = (char*)d_ws;
  size_t off = 0;
  auto alloc = [&](size_t nb) {
    char* p = ws + off;
    off += (nb + 255) & ~(size_t)255;
    return p;
  };
  _Float16* qkf = (_Float16*)alloc((size_t)Bb * Nn * C4 * 2);
  _Float16* xvf = (_Float16*)alloc((size_t)Bb * Cc * Nn * 2);
  float* stats = (float*)alloc((size_t)Bb * Nn * 4);
  _Float16* wqkh = (_Float16*)alloc((size_t)C4 * Cc * 2);
  _Float16* wqkl = (_Float16*)alloc((size_t)C4 * Cc * 2);
  _Float16* wvf = (_Float16*)alloc((size_t)Cc * Cc * 2);
  _Float16* wtf = (_Float16*)alloc((size_t)Cc * Cc * 2);

  k0_weights<<<dim3(256), dim3(256), 0, stream>>>(wqk, wv, wt, wqkh, wqkl, wvf, wtf);
  k23_qkv<<<dim3(512), dim3(512), 0, stream>>>(x, wqkh, wqkl, wvf, bv, qkf, xvf);
  k4_stats<<<dim3(512), dim3(512), 0, stream>>>(qkf, stats);
  k5_main<<<dim3(512), dim3(512), 0, stream>>>(x, qkf, xvf, stats, wtf, bt,
                                               gamma, beta, rmean, rvar, out);
}

// Round 8
// 164.887 us; speedup vs baseline: 1.6850x; 1.1583x over previous
//
#include <hip/hip_runtime.h>

#define Bb 8
#define Cc 256
#define C4 64
#define Nn 4096

typedef _Float16 half8 __attribute__((ext_vector_type(8)));
typedef float f32x4 __attribute__((ext_vector_type(4)));
typedef unsigned int u32;

__device__ __forceinline__ f32x4 fz4() {
  f32x4 z; z[0] = 0.f; z[1] = 0.f; z[2] = 0.f; z[3] = 0.f; return z;
}
__device__ __forceinline__ f32x4 mfma16(half8 a, half8 b, f32x4 c) {
  return __builtin_amdgcn_mfma_f32_16x16x32_f16(a, b, c, 0, 0, 0);
}
__device__ __forceinline__ u32 pkrtz(float a, float b) {
  typedef __fp16 h2n __attribute__((ext_vector_type(2)));
  h2n h = __builtin_amdgcn_cvt_pkrtz(a, b);
  return __builtin_bit_cast(u32, h);
}
__device__ __forceinline__ void gll16(const void* g, void* l) {
  __builtin_amdgcn_global_load_lds(
      (const __attribute__((address_space(1))) u32*)g,
      (__attribute__((address_space(3))) u32*)l, 16, 0, 0);
}

// Fragment-tiled f16 layout: tile = 16 rows x 32 k, 1KB, internally [l4][row&15][k&7].
// frag byte offset for (row r, k) given row-tile index rt and k-tile index kt (k/32):
//   byte = (tile_linear)*1024 + ((k>>3)&3)*256 + (r&15)*16 + (k&7)*2

// ---------------- K0: weight prep -> fragment-tiled f16 (w_qk hi/lo, log2-scaled) ------
__global__ void k0_weights(const float* __restrict__ wqk, const float* __restrict__ wv,
                           const float* __restrict__ wt,
                           _Float16* __restrict__ wqkh, _Float16* __restrict__ wqkl,
                           _Float16* __restrict__ wvf, _Float16* __restrict__ wtf) {
  int idx = blockIdx.x * 256 + threadIdx.x;
  if (idx < C4 * Cc) {
    int o = idx >> 8, c = idx & 255;
    float f = wqk[idx] * 1.2011224087864498f;  // 1/sqrt(ln2): E' = E/ln2
    _Float16 h = (_Float16)f;
    int off = ((((o >> 4) * 8 + (c >> 5)) * 4 + ((c >> 3) & 3)) * 16 + (o & 15)) * 8 + (c & 7);
    wqkh[off] = h;
    wqkl[off] = (_Float16)(f - (float)h);
  }
  if (idx < Cc * Cc) {
    int o = idx >> 8, k = idx & 255;
    int off = ((((o >> 4) * 8 + (k >> 5)) * 4 + ((k >> 3) & 3)) * 16 + (o & 15)) * 8 + (k & 7);
    wvf[off] = (_Float16)wv[idx];
    wtf[off] = (_Float16)wt[idx];
  }
}

// ---------------- K23: qk + x_v, outputs fragment-tiled ----------------
// qkf: per batch 256 n-tiles x 2 k-tiles x 1KB (512KB/b). xvf: 16 c-tiles x 128 n-tiles (2MB/b).
__global__ __launch_bounds__(512) void k23_qkv(
    const float* __restrict__ x,
    const _Float16* __restrict__ wqkh, const _Float16* __restrict__ wqkl,
    const _Float16* __restrict__ wvf, const float* __restrict__ bv,
    _Float16* __restrict__ qkf, _Float16* __restrict__ xvf) {
  __shared__ _Float16 xh[64 * 264];  // [n][c] transposed x (single f16; lo-split dropped)
  const int bid = blockIdx.x;
  const int b = bid & 7, n0 = (bid >> 3) * 64, tid = threadIdx.x;
  {
    const int cc = tid >> 3, nn = (tid & 7) * 8;
    #pragma unroll
    for (int ph = 0; ph < 4; ++ph) {
      int c = cc + ph * 64;
      const float* src = x + ((size_t)(b * Cc + c)) * Nn + n0 + nn;
      float4 v0 = *(const float4*)(src);
      float4 v1 = *(const float4*)(src + 4);
      float vv[8] = {v0.x, v0.y, v0.z, v0.w, v1.x, v1.y, v1.z, v1.w};
      #pragma unroll
      for (int j = 0; j < 8; ++j) xh[(nn + j) * 264 + c] = (_Float16)vv[j];
    }
  }
  __syncthreads();
  const int w = tid >> 6, lane = tid & 63, l15 = lane & 15, l4 = lane >> 4;
  // ---- q: out [64 n][64 o], K=256; 2-term (x_h*w_h + x_h*w_l) ----
  {
    const int fn = w >> 1, ob = (w & 1) * 32;
    f32x4 acc[2] = {fz4(), fz4()};
    #pragma unroll
    for (int kb = 0; kb < 8; ++kb) {
      half8 ah = *(const half8*)(xh + (fn * 16 + l15) * 264 + kb * 32 + l4 * 8);
      #pragma unroll
      for (int f = 0; f < 2; ++f) {
        const int ot = (ob >> 4) + f;
        half8 bh = *(const half8*)((const char*)wqkh + (ot * 8 + kb) * 1024 + lane * 16);
        half8 bl = *(const half8*)((const char*)wqkl + (ot * 8 + kb) * 1024 + lane * 16);
        acc[f] = mfma16(ah, bh, acc[f]);
        acc[f] = mfma16(ah, bl, acc[f]);
      }
    }
    #pragma unroll
    for (int f = 0; f < 2; ++f)
      #pragma unroll
      for (int i = 0; i < 4; ++i) {
        const int n = n0 + fn * 16 + l4 * 4 + i;
        const int o = ob + f * 16 + l15;
        int off = ((((b * 256 + (n >> 4)) * 2 + (o >> 5)) * 4 + ((o >> 3) & 3)) * 16 +
                   (n & 15)) * 8 + (o & 7);
        qkf[off] = (_Float16)acc[f][i];
      }
  }
  // ---- x_v: out [256 c][64 n], K=256 ----
  {
    const int cb = w * 32;
    f32x4 acc[2][4];
    #pragma unroll
    for (int a = 0; a < 2; ++a)
      #pragma unroll
      for (int q = 0; q < 4; ++q) acc[a][q] = fz4();
    #pragma unroll
    for (int kb = 0; kb < 8; ++kb) {
      half8 bfr[4];
      #pragma unroll
      for (int fnb = 0; fnb < 4; ++fnb)
        bfr[fnb] = *(const half8*)(xh + (fnb * 16 + l15) * 264 + kb * 32 + l4 * 8);
      #pragma unroll
      for (int fc = 0; fc < 2; ++fc) {
        const int ct = (cb >> 4) + fc;
        half8 a = *(const half8*)((const char*)wvf + (ct * 8 + kb) * 1024 + lane * 16);
        #pragma unroll
        for (int fnb = 0; fnb < 4; ++fnb)
          acc[fc][fnb] = mfma16(a, bfr[fnb], acc[fc][fnb]);
      }
    }
    #pragma unroll
    for (int fc = 0; fc < 2; ++fc)
      #pragma unroll
      for (int fnb = 0; fnb < 4; ++fnb)
        #pragma unroll
        for (int i = 0; i < 4; ++i) {
          const int c = cb + fc * 16 + l4 * 4 + i;
          const int n = n0 + fnb * 16 + l15;
          int off = ((((b * 16 + (c >> 4)) * 128 + (n >> 5)) * 4 + ((n >> 3) & 3)) * 16 +
                     (c & 15)) * 8 + (n & 7);
          xvf[off] = (_Float16)(acc[fc][fnb][i] + bv[c]);
        }
  }
}

// ---------------- K4: softmax row stats  a'_n = 32 + log2(sum 2^(E'-32)) ----------------
// Zero in-loop LDS/barriers; all frag loads are contiguous 1KB/wave; pointer induction.
__global__ __launch_bounds__(512, 4) void k4_stats(
    const _Float16* __restrict__ qkf, float* __restrict__ stats) {
  __shared__ float red[64][8];
  const int bid = blockIdx.x;
  const int b = bid & 7, n0 = (bid >> 3) * 64, tid = threadIdx.x;
  const int w = tid >> 6, lane = tid & 63, l15 = lane & 15, l4 = lane >> 4;
  const char* qbt = (const char*)qkf + (size_t)b * 524288;

  half8 qn_r[2][4];
  #pragma unroll
  for (int kb = 0; kb < 2; ++kb)
    #pragma unroll
    for (int fn = 0; fn < 4; ++fn)
      qn_r[kb][fn] = *(const half8*)(qbt + (((n0 >> 4) + fn) * 2 + kb) * 1024 + lane * 16);

  const char* qp = qbt + w * 2048 + lane * 16;  // qm tile (it*8 + w), kb in {0,1}
  half8 qa0 = *(const half8*)qp;
  half8 qa1 = *(const half8*)(qp + 1024);

  float sm[4] = {0.f, 0.f, 0.f, 0.f};
  for (int it = 0; it < 32; ++it) {
    f32x4 g[4] = {fz4(), fz4(), fz4(), fz4()};
    #pragma unroll
    for (int fn = 0; fn < 4; ++fn) g[fn] = mfma16(qa0, qn_r[0][fn], g[fn]);
    #pragma unroll
    for (int fn = 0; fn < 4; ++fn) g[fn] = mfma16(qa1, qn_r[1][fn], g[fn]);
    if (it < 31) qp += 16384;
    qa0 = *(const half8*)qp;
    qa1 = *(const half8*)(qp + 1024);
    #pragma unroll
    for (int fn = 0; fn < 4; ++fn)
      #pragma unroll
      for (int i = 0; i < 4; ++i)
        sm[fn] += exp2f(g[fn][i] - 32.0f);
  }
  #pragma unroll
  for (int fn = 0; fn < 4; ++fn) {
    sm[fn] += __shfl_xor(sm[fn], 16, 64);
    sm[fn] += __shfl_xor(sm[fn], 32, 64);
  }
  if (l4 == 0) {
    #pragma unroll
    for (int fn = 0; fn < 4; ++fn) red[fn * 16 + l15][w] = sm[fn];
  }
  __syncthreads();
  if (tid < 64) {
    float t = 0.f;
    #pragma unroll
    for (int j = 0; j < 8; ++j) t += red[tid][j];
    stats[(size_t)b * Nn + n0 + tid] = 32.0f + log2f(t);
  }
}

// ---------------- K5: fused attention-apply + conv_t + BN + ReLU + residual ----------------
// r7 structure (1 barrier/iter, vmcnt(2), qn 3-buf 2-iter lead, xv wave-private), but all
// global/gll accesses are contiguous frag tiles with pointer induction; no LDS-read XOR.
__global__ __launch_bounds__(512, 4) void k5_main(
    const float* __restrict__ x,
    const _Float16* __restrict__ qkf, const _Float16* __restrict__ xvf,
    const float* __restrict__ stats,
    const _Float16* __restrict__ wtf, const float* __restrict__ bt,
    const float* __restrict__ gamma, const float* __restrict__ beta,
    const float* __restrict__ rmean, const float* __restrict__ rvar,
    float* __restrict__ out) {
  // [0,24K): qn 3 bufs (8K: 4 n-tiles x 2 kb x 1KB) | [24K,40K): PT dbuf | [40K,72K): xv 8x4K
  __shared__ __align__(16) char smem[73728];
  const int bid = blockIdx.x;
  const int b = bid & 7, m0 = (bid >> 3) * 64, tid = threadIdx.x;
  const int w = tid >> 6, lane = tid & 63, l15 = lane & 15, l4 = lane >> 4;
  const int wa = w >> 2;  // G: m 32-block
  const int wb = w & 3;   // G: n 16-block
  const size_t bq = (size_t)b * Nn;
  const char* qkt = (const char*)qkf + (size_t)b * 524288;
  const char* xvt = (const char*)xvf + (size_t)b * 2097152;
  const int key = l15 & 7;
  char* xvw = smem + 40960 + (w << 12);

  // stationary qm (B-op rows m0 + wa*32 + fm*16 + l15): contiguous frag loads
  half8 qm_r[2][2];
  #pragma unroll
  for (int kb = 0; kb < 2; ++kb)
    #pragma unroll
    for (int fm = 0; fm < 2; ++fm)
      qm_r[kb][fm] = *(const half8*)(qkt + (((m0 >> 4) + wa * 2 + fm) * 2 + kb) * 1024 +
                                     lane * 16);

  // induction pointers
  const char* qnsrc = qkt + 16384 + (size_t)tid * 16;       // qn[it+2] (8KB/iter)
  const char* xvsrc[4];
  #pragma unroll
  for (int j = 0; j < 4; ++j)
    xvsrc[j] = xvt + ((w * 2 + (j >> 1)) * 128 + (j & 1)) * 1024 + (size_t)lane * 16;
  const float* anp = stats + bq + wb * 16 + l4 * 4;

  f32x4 acc[4][2];
  #pragma unroll
  for (int a = 0; a < 4; ++a)
    #pragma unroll
    for (int q = 0; q < 2; ++q) acc[a][q] = fz4();

  // prologue: qn[0]->buf0, qn[1]->buf1, xv[0], an[0]
  gll16(qkt + (size_t)tid * 16, smem + w * 1024);
  gll16(qkt + 8192 + (size_t)tid * 16, smem + 8192 + w * 1024);
  #pragma unroll
  for (int j = 0; j < 4; ++j) gll16(xvsrc[j], xvw + j * 1024);
  float4 an = *(const float4*)anp;
  asm volatile("s_waitcnt vmcnt(0) lgkmcnt(0)" ::: "memory");
  __builtin_amdgcn_sched_barrier(0);
  __builtin_amdgcn_s_barrier();

  int br = 0, bw = 2;
  for (int it = 0; it < 64; ++it) {
    // stage qn[it+2]
    gll16(qnsrc, smem + bw * 8192 + w * 1024);
    if (it < 61) qnsrc += 8192;
    bw = bw == 2 ? 0 : bw + 1;
    // ---- G: rows n (wb*16+l4*4+i), cols m (wa*32+fm*16+l15) ----
    const char* qb = smem + br * 8192;
    br = br == 2 ? 0 : br + 1;
    f32x4 g0 = fz4(), g1 = fz4();
    #pragma unroll
    for (int kb = 0; kb < 2; ++kb) {
      half8 ah = *(const half8*)(qb + wb * 2048 + kb * 1024 + lane * 16);
      g0 = mfma16(ah, qm_r[kb][0], g0);
      g1 = mfma16(ah, qm_r[kb][1], g1);
    }
    // ---- P = 2^(E' - a'_n) -> PT (swizzled transpose write) ----
    char* PTp = smem + 24576 + ((it & 1) << 13);
    {
      uint2 pk;
      pk.x = pkrtz(exp2f(g0[0] - an.x), exp2f(g0[1] - an.y));
      pk.y = pkrtz(exp2f(g0[2] - an.z), exp2f(g0[3] - an.w));
      *(uint2*)(PTp + (wa * 32 + l15) * 128 + ((wb * 32 + l4 * 8) ^ (key << 4))) = pk;
      pk.x = pkrtz(exp2f(g1[0] - an.x), exp2f(g1[1] - an.y));
      pk.y = pkrtz(exp2f(g1[2] - an.z), exp2f(g1[3] - an.w));
      *(uint2*)(PTp + (wa * 32 + 16 + l15) * 128 + ((wb * 32 + l4 * 8) ^ (key << 4))) = pk;
    }
    if (it < 63) anp += 64;
    an = *(const float4*)anp;
    // ---- single barrier: PT visible; xv[it]+qn[it+1] drained (qn[it+2], an in flight) ----
    asm volatile("s_waitcnt vmcnt(2) lgkmcnt(0)" ::: "memory");
    __builtin_amdgcn_sched_barrier(0);
    __builtin_amdgcn_s_barrier();
    // ---- PV: x_r^T[m][c] += P[m][n]*xv[c][n]; wave = m64 x private c32 ----
    __builtin_amdgcn_s_setprio(1);
    #pragma unroll
    for (int kb = 0; kb < 2; ++kb) {
      half8 pa[4], xb[2];
      #pragma unroll
      for (int fm = 0; fm < 4; ++fm)
        pa[fm] = *(const half8*)(PTp + (fm * 16 + l15) * 128 + (((kb * 4 + l4) ^ key) * 16));
      #pragma unroll
      for (int fc = 0; fc < 2; ++fc)
        xb[fc] = *(const half8*)(xvw + (fc * 2 + kb) * 1024 + lane * 16);
      #pragma unroll
      for (int fm = 0; fm < 4; ++fm)
        #pragma unroll
        for (int fc = 0; fc < 2; ++fc)
          acc[fm][fc] = mfma16(pa[fm], xb[fc], acc[fm][fc]);
    }
    __builtin_amdgcn_s_setprio(0);
    // re-stage own xv[it+1] (wave-local)
    asm volatile("s_waitcnt lgkmcnt(0)" ::: "memory");
    __builtin_amdgcn_sched_barrier(0);
    if (it < 63) {
      #pragma unroll
      for (int j = 0; j < 4; ++j) xvsrc[j] += 2048;
    }
    #pragma unroll
    for (int j = 0; j < 4; ++j) gll16(xvsrc[j], xvw + j * 1024);
  }
  asm volatile("s_waitcnt vmcnt(0) lgkmcnt(0)" ::: "memory");
  __builtin_amdgcn_sched_barrier(0);
  __builtin_amdgcn_s_barrier();

  // ---- Epilogue: s^T = x - x_r^T into st[64][264] f16 ----
  _Float16* st = (_Float16*)smem;
  #pragma unroll
  for (int fm = 0; fm < 4; ++fm)
    #pragma unroll
    for (int fc = 0; fc < 2; ++fc) {
      int c = w * 32 + fc * 16 + l15;
      const float* xp = x + ((size_t)b * Cc + c) * Nn + m0 + fm * 16 + l4 * 4;
      float4 v = *(const float4*)xp;
      float vv[4] = {v.x, v.y, v.z, v.w};
      #pragma unroll
      for (int i = 0; i < 4; ++i) {
        int m = fm * 16 + l4 * 4 + i;
        st[m * 264 + c] = (_Float16)(vv[i] - acc[fm][fc][i]);
      }
    }
  __syncthreads();
  // ---- t = w_t . s + b_t, BN, ReLU, +x ----
  {
    const int ob = (w >> 1) * 64, mb2 = (w & 1) * 32;
    f32x4 t[4][2];
    #pragma unroll
    for (int a = 0; a < 4; ++a)
      #pragma unroll
      for (int q = 0; q < 2; ++q) t[a][q] = fz4();
    #pragma unroll
    for (int kb = 0; kb < 8; ++kb) {
      half8 bfr[2];
      #pragma unroll
      for (int fm2 = 0; fm2 < 2; ++fm2)
        bfr[fm2] = *(const half8*)(st + (mb2 + fm2 * 16 + l15) * 264 + kb * 32 + l4 * 8);
      #pragma unroll
      for (int fo = 0; fo < 4; ++fo) {
        const int ot = (ob >> 4) + fo;
        half8 a = *(const half8*)((const char*)wtf + (ot * 8 + kb) * 1024 + lane * 16);
        #pragma unroll
        for (int fm2 = 0; fm2 < 2; ++fm2)
          t[fo][fm2] = mfma16(a, bfr[fm2], t[fo][fm2]);
      }
    }
    #pragma unroll
    for (int fo = 0; fo < 4; ++fo)
      #pragma unroll
      for (int i = 0; i < 4; ++i) {
        const int o = ob + fo * 16 + l4 * 4 + i;
        const float inv = gamma[o] * rsqrtf(rvar[o] + 1e-5f);
        const float addv = beta[o] - rmean[o] * inv;
        const float btv = bt[o];
        #pragma unroll
        for (int fm2 = 0; fm2 < 2; ++fm2) {
          const int m = m0 + mb2 + fm2 * 16 + l15;
          float tv = t[fo][fm2][i] + btv;
          float bn = tv * inv + addv;
          float xr = x[((size_t)b * Cc + o) * Nn + m];
          out[((size_t)b * Cc + o) * Nn + m] = xr + fmaxf(bn, 0.0f);
        }
      }
  }
}

extern "C" void kernel_launch(void* const* d_in, const int* in_sizes, int n_in,
                              void* d_out, int out_size, void* d_ws, size_t ws_size,
                              hipStream_t stream) {
  const float* x = (const float*)d_in[0];
  const float* wqk = (const float*)d_in[1];
  const float* wv = (const float*)d_in[2];
  const float* bv = (const float*)d_in[3];
  const float* wt = (const float*)d_in[4];
  const float* bt = (const float*)d_in[5];
  const float* gamma = (const float*)d_in[6];
  const float* beta = (const float*)d_in[7];
  const float* rmean = (const float*)d_in[8];
  const float* rvar = (const float*)d_in[9];
  float* out = (float*)d_out;

  char* ws = (char*)d_ws;
  size_t off = 0;
  auto alloc = [&](size_t nb) {
    char* p = ws + off;
    off += (nb + 255) & ~(size_t)255;
    return p;
  };
  _Float16* qkf = (_Float16*)alloc((size_t)Bb * Nn * C4 * 2);
  _Float16* xvf = (_Float16*)alloc((size_t)Bb * Cc * Nn * 2);
  float* stats = (float*)alloc((size_t)Bb * Nn * 4);
  _Float16* wqkh = (_Float16*)alloc((size_t)C4 * Cc * 2);
  _Float16* wqkl = (_Float16*)alloc((size_t)C4 * Cc * 2);
  _Float16* wvf = (_Float16*)alloc((size_t)Cc * Cc * 2);
  _Float16* wtf = (_Float16*)alloc((size_t)Cc * Cc * 2);

  k0_weights<<<dim3(256), dim3(256), 0, stream>>>(wqk, wv, wt, wqkh, wqkl, wvf, wtf);
  k23_qkv<<<dim3(512), dim3(512), 0, stream>>>(x, wqkh, wqkl, wvf, bv, qkf, xvf);
  k4_stats<<<dim3(512), dim3(512), 0, stream>>>(qkf, stats);
  k5_main<<<dim3(512), dim3(512), 0, stream>>>(x, qkf, xvf, stats, wtf, bt,
                                               gamma, beta, rmean, rvar, out);
}

// Round 9
// 149.226 us; speedup vs baseline: 1.8619x; 1.1050x over previous
//
#include <hip/hip_runtime.h>

#define Bb 8
#define Cc 256
#define C4 64
#define Nn 4096

typedef _Float16 half8 __attribute__((ext_vector_type(8)));
typedef float f32x4 __attribute__((ext_vector_type(4)));
typedef unsigned int u32;

__device__ __forceinline__ f32x4 fz4() {
  f32x4 z; z[0] = 0.f; z[1] = 0.f; z[2] = 0.f; z[3] = 0.f; return z;
}
__device__ __forceinline__ f32x4 mfma16(half8 a, half8 b, f32x4 c) {
  return __builtin_amdgcn_mfma_f32_16x16x32_f16(a, b, c, 0, 0, 0);
}
__device__ __forceinline__ u32 pkrtz(float a, float b) {
  typedef __fp16 h2n __attribute__((ext_vector_type(2)));
  h2n h = __builtin_amdgcn_cvt_pkrtz(a, b);
  return __builtin_bit_cast(u32, h);
}
__device__ __forceinline__ float ex2(float x) {
  float r;
  asm("v_exp_f32 %0, %1" : "=v"(r) : "v"(x));
  return r;
}
__device__ __forceinline__ void gll16(const void* g, void* l) {
  __builtin_amdgcn_global_load_lds(
      (const __attribute__((address_space(1))) u32*)g,
      (__attribute__((address_space(3))) u32*)l, 16, 0, 0);
}

// Fragment-tiled f16 layout: tile = 16 rows x 32 k = 1KB, internally [k>>3&3][row&15][k&7].

// ---------------- K0: weight prep -> fragment-tiled f16 (w_qk hi/lo, log2-scaled) ------
__global__ void k0_weights(const float* __restrict__ wqk, const float* __restrict__ wv,
                           const float* __restrict__ wt,
                           _Float16* __restrict__ wqkh, _Float16* __restrict__ wqkl,
                           _Float16* __restrict__ wvf, _Float16* __restrict__ wtf) {
  int idx = blockIdx.x * 256 + threadIdx.x;
  if (idx < C4 * Cc) {
    int o = idx >> 8, c = idx & 255;
    float f = wqk[idx] * 1.2011224087864498f;  // 1/sqrt(ln2): E' = E/ln2
    _Float16 h = (_Float16)f;
    int off = ((((o >> 4) * 8 + (c >> 5)) * 4 + ((c >> 3) & 3)) * 16 + (o & 15)) * 8 + (c & 7);
    wqkh[off] = h;
    wqkl[off] = (_Float16)(f - (float)h);
  }
  if (idx < Cc * Cc) {
    int o = idx >> 8, k = idx & 255;
    int off = ((((o >> 4) * 8 + (k >> 5)) * 4 + ((k >> 3) & 3)) * 16 + (o & 15)) * 8 + (k & 7);
    wvf[off] = (_Float16)wv[idx];
    wtf[off] = (_Float16)wt[idx];
  }
}

// ---------------- K23: qk + x_v, outputs fragment-tiled ----------------
__global__ __launch_bounds__(512) void k23_qkv(
    const float* __restrict__ x,
    const _Float16* __restrict__ wqkh, const _Float16* __restrict__ wqkl,
    const _Float16* __restrict__ wvf, const float* __restrict__ bv,
    _Float16* __restrict__ qkf, _Float16* __restrict__ xvf) {
  __shared__ _Float16 xh[64 * 264];  // [n][c] transposed x
  const int bid = blockIdx.x;
  const int b = bid & 7, n0 = (bid >> 3) * 64, tid = threadIdx.x;
  {
    const int cc = tid >> 3, nn = (tid & 7) * 8;
    #pragma unroll
    for (int ph = 0; ph < 4; ++ph) {
      int c = cc + ph * 64;
      const float* src = x + ((size_t)(b * Cc + c)) * Nn + n0 + nn;
      float4 v0 = *(const float4*)(src);
      float4 v1 = *(const float4*)(src + 4);
      float vv[8] = {v0.x, v0.y, v0.z, v0.w, v1.x, v1.y, v1.z, v1.w};
      #pragma unroll
      for (int j = 0; j < 8; ++j) xh[(nn + j) * 264 + c] = (_Float16)vv[j];
    }
  }
  __syncthreads();
  const int w = tid >> 6, lane = tid & 63, l15 = lane & 15, l4 = lane >> 4;
  {
    const int fn = w >> 1, ob = (w & 1) * 32;
    f32x4 acc[2] = {fz4(), fz4()};
    #pragma unroll
    for (int kb = 0; kb < 8; ++kb) {
      half8 ah = *(const half8*)(xh + (fn * 16 + l15) * 264 + kb * 32 + l4 * 8);
      #pragma unroll
      for (int f = 0; f < 2; ++f) {
        const int ot = (ob >> 4) + f;
        half8 bh = *(const half8*)((const char*)wqkh + (ot * 8 + kb) * 1024 + lane * 16);
        half8 bl = *(const half8*)((const char*)wqkl + (ot * 8 + kb) * 1024 + lane * 16);
        acc[f] = mfma16(ah, bh, acc[f]);
        acc[f] = mfma16(ah, bl, acc[f]);
      }
    }
    #pragma unroll
    for (int f = 0; f < 2; ++f)
      #pragma unroll
      for (int i = 0; i < 4; ++i) {
        const int n = n0 + fn * 16 + l4 * 4 + i;
        const int o = ob + f * 16 + l15;
        int off = ((((b * 256 + (n >> 4)) * 2 + (o >> 5)) * 4 + ((o >> 3) & 3)) * 16 +
                   (n & 15)) * 8 + (o & 7);
        qkf[off] = (_Float16)acc[f][i];
      }
  }
  {
    const int cb = w * 32;
    f32x4 acc[2][4];
    #pragma unroll
    for (int a = 0; a < 2; ++a)
      #pragma unroll
      for (int q = 0; q < 4; ++q) acc[a][q] = fz4();
    #pragma unroll
    for (int kb = 0; kb < 8; ++kb) {
      half8 bfr[4];
      #pragma unroll
      for (int fnb = 0; fnb < 4; ++fnb)
        bfr[fnb] = *(const half8*)(xh + (fnb * 16 + l15) * 264 + kb * 32 + l4 * 8);
      #pragma unroll
      for (int fc = 0; fc < 2; ++fc) {
        const int ct = (cb >> 4) + fc;
        half8 a = *(const half8*)((const char*)wvf + (ct * 8 + kb) * 1024 + lane * 16);
        #pragma unroll
        for (int fnb = 0; fnb < 4; ++fnb)
          acc[fc][fnb] = mfma16(a, bfr[fnb], acc[fc][fnb]);
      }
    }
    #pragma unroll
    for (int fc = 0; fc < 2; ++fc)
      #pragma unroll
      for (int fnb = 0; fnb < 4; ++fnb)
        #pragma unroll
        for (int i = 0; i < 4; ++i) {
          const int c = cb + fc * 16 + l4 * 4 + i;
          const int n = n0 + fnb * 16 + l15;
          int off = ((((b * 16 + (c >> 4)) * 128 + (n >> 5)) * 4 + ((n >> 3) & 3)) * 16 +
                     (c & 15)) * 8 + (n & 7);
          xvf[off] = (_Float16)(acc[fc][fnb][i] + bv[c]);
        }
  }
}

// ---------------- K4: softmax row stats  a'_n = 32 + log2(sum 2^(E'-32)) ----------------
__global__ __launch_bounds__(512, 4) void k4_stats(
    const _Float16* __restrict__ qkf, float* __restrict__ stats) {
  __shared__ float red[64][8];
  const int bid = blockIdx.x;
  const int b = bid & 7, n0 = (bid >> 3) * 64, tid = threadIdx.x;
  const int w = tid >> 6, lane = tid & 63, l15 = lane & 15, l4 = lane >> 4;
  const char* qbt = (const char*)qkf + (size_t)b * 524288;

  half8 qn_r[2][4];
  #pragma unroll
  for (int kb = 0; kb < 2; ++kb)
    #pragma unroll
    for (int fn = 0; fn < 4; ++fn)
      qn_r[kb][fn] = *(const half8*)(qbt + (((n0 >> 4) + fn) * 2 + kb) * 1024 + lane * 16);

  const char* qp = qbt + w * 2048 + lane * 16;
  half8 qa0 = *(const half8*)qp;
  half8 qa1 = *(const half8*)(qp + 1024);

  float sm[4] = {0.f, 0.f, 0.f, 0.f};
  for (int it = 0; it < 32; ++it) {
    f32x4 g[4] = {fz4(), fz4(), fz4(), fz4()};
    #pragma unroll
    for (int fn = 0; fn < 4; ++fn) g[fn] = mfma16(qa0, qn_r[0][fn], g[fn]);
    #pragma unroll
    for (int fn = 0; fn < 4; ++fn) g[fn] = mfma16(qa1, qn_r[1][fn], g[fn]);
    if (it < 31) qp += 16384;
    qa0 = *(const half8*)qp;
    qa1 = *(const half8*)(qp + 1024);
    #pragma unroll
    for (int fn = 0; fn < 4; ++fn)
      #pragma unroll
      for (int i = 0; i < 4; ++i)
        sm[fn] += ex2(g[fn][i] - 32.0f);
  }
  #pragma unroll
  for (int fn = 0; fn < 4; ++fn) {
    sm[fn] += __shfl_xor(sm[fn], 16, 64);
    sm[fn] += __shfl_xor(sm[fn], 32, 64);
  }
  if (l4 == 0) {
    #pragma unroll
    for (int fn = 0; fn < 4; ++fn) red[fn * 16 + l15][w] = sm[fn];
  }
  __syncthreads();
  if (tid < 64) {
    float t = 0.f;
    #pragma unroll
    for (int j = 0; j < 8; ++j) t += red[tid][j];
    stats[(size_t)b * Nn + n0 + tid] = 32.0f + log2f(t);
  }
}

// ---------------- K5: m128 x c256 block tile, 1 block/CU ----------------
// LDS/iter halved per MFMA vs r8: wave = m64xc64 in PV (acc 4x4), m64xn16 in G.
// qn 3-buf gll 2-iter lead; PT dbuf 16KB; xv dbuf 32KB; 1 counted-vmcnt barrier/iter.
__global__ __launch_bounds__(512, 2) void k5_main(
    const float* __restrict__ x,
    const _Float16* __restrict__ qkf, const _Float16* __restrict__ xvf,
    const float* __restrict__ stats,
    const _Float16* __restrict__ wtf, const float* __restrict__ bt,
    const float* __restrict__ gamma, const float* __restrict__ beta,
    const float* __restrict__ rmean, const float* __restrict__ rvar,
    float* __restrict__ out) {
  // [0,24K) qn 3x8K | [24K,56K) PT dbuf 2x16K | [56K,120K) xv dbuf 2x32K
  __shared__ __align__(16) char smem[122880];
  const int bid = blockIdx.x;
  const int b = bid & 7, m0 = (bid >> 3) * 128, tid = threadIdx.x;
  const int w = tid >> 6, lane = tid & 63, l15 = lane & 15, l4 = lane >> 4;
  const int wa = w >> 2;  // m 64-half
  const int wb = w & 3;   // G: n16 quarter; PV: c64 quarter
  const size_t bq = (size_t)b * Nn;
  const char* qkt = (const char*)qkf + (size_t)b * 524288;
  const char* xvt = (const char*)xvf + (size_t)b * 2097152;
  const int key = l15 & 7;

  // stationary qm: B-operand frags for wave's m64 (4 m-tiles x 2 kb)
  half8 qm_r[2][4];
  #pragma unroll
  for (int kb = 0; kb < 2; ++kb)
    #pragma unroll
    for (int fm = 0; fm < 4; ++fm)
      qm_r[kb][fm] = *(const half8*)(qkt + ((((m0 >> 4) + wa * 4 + fm) * 2) + kb) * 1024 +
                                     lane * 16);

  // induction pointers
  const char* qnsrc = qkt + 16384 + (size_t)tid * 16;             // qn[it+2], +8192/iter
  const char* xvp = xvt + (size_t)w * 262144 + (size_t)lane * 16; // xv[it], +2048/iter
  const float* anp = stats + bq + wb * 16 + l4 * 4;

  f32x4 acc[4][4];  // [fm m16 of m64][fc c16 of c64]
  #pragma unroll
  for (int a = 0; a < 4; ++a)
    #pragma unroll
    for (int q = 0; q < 4; ++q) acc[a][q] = fz4();

  // prologue: qn[0]->buf0, qn[1]->buf1, xv[0]->xbuf0, an[0]
  gll16(qkt + (size_t)tid * 16, smem + w * 1024);
  gll16(qkt + 8192 + (size_t)tid * 16, smem + 8192 + w * 1024);
  #pragma unroll
  for (int j = 0; j < 4; ++j)
    gll16(xvp + (j >> 1) * 131072 + (j & 1) * 1024, smem + 57344 + (w * 4 + j) * 1024);
  float4 an = *(const float4*)anp;
  asm volatile("s_waitcnt vmcnt(0) lgkmcnt(0)" ::: "memory");
  __builtin_amdgcn_sched_barrier(0);
  __builtin_amdgcn_s_barrier();

  int br = 0, bw = 2;
  for (int it = 0; it < 64; ++it) {
    // stage qn[it+2]
    gll16(qnsrc, smem + bw * 8192 + w * 1024);
    if (it < 61) qnsrc += 8192;
    bw = bw == 2 ? 0 : bw + 1;
    // ---- G: D[n16][m64] = mfma(qn_frag, qm_frag); wave rows n = wb*16, cols m = wa*64 ----
    const char* qb = smem + br * 8192;
    br = br == 2 ? 0 : br + 1;
    f32x4 g[4] = {fz4(), fz4(), fz4(), fz4()};
    #pragma unroll
    for (int kb = 0; kb < 2; ++kb) {
      half8 ah = *(const half8*)(qb + (wb * 2 + kb) * 1024 + lane * 16);
      #pragma unroll
      for (int fm = 0; fm < 4; ++fm)
        g[fm] = mfma16(ah, qm_r[kb][fm], g[fm]);
    }
    // ---- P = 2^(E' - a'_n) -> PT[m128][n64] (swizzled rows of 128B) ----
    char* PTp = smem + 24576 + ((it & 1) << 14);
    #pragma unroll
    for (int fm = 0; fm < 4; ++fm) {
      uint2 pk;
      pk.x = pkrtz(ex2(g[fm][0] - an.x), ex2(g[fm][1] - an.y));
      pk.y = pkrtz(ex2(g[fm][2] - an.z), ex2(g[fm][3] - an.w));
      *(uint2*)(PTp + (wa * 64 + fm * 16 + l15) * 128 +
                ((wb * 32 + l4 * 8) ^ (key << 4))) = pk;
    }
    if (it < 63) anp += 64;
    an = *(const float4*)anp;
    // ---- single barrier: PT visible; xv[it]+qn[it+1] drained (qn[it+2]+an in flight) ----
    asm volatile("s_waitcnt vmcnt(2) lgkmcnt(0)" ::: "memory");
    __builtin_amdgcn_sched_barrier(0);
    __builtin_amdgcn_s_barrier();
    // ---- PV: acc[m64][c64] += P[m][n] * xv[c][n] ----
    const char* xvR = smem + 57344 + ((it & 1) << 15);
    __builtin_amdgcn_s_setprio(1);
    #pragma unroll
    for (int kb = 0; kb < 2; ++kb) {
      half8 pa[4], xb[4];
      #pragma unroll
      for (int fm = 0; fm < 4; ++fm)
        pa[fm] = *(const half8*)(PTp + (wa * 64 + fm * 16 + l15) * 128 +
                                 (((kb * 4 + l4) ^ key) * 16));
      #pragma unroll
      for (int fc = 0; fc < 4; ++fc)
        xb[fc] = *(const half8*)(xvR + ((wb * 4 + fc) * 2 + kb) * 1024 + lane * 16);
      #pragma unroll
      for (int fm = 0; fm < 4; ++fm)
        #pragma unroll
        for (int fc = 0; fc < 4; ++fc)
          acc[fm][fc] = mfma16(pa[fm], xb[fc], acc[fm][fc]);
    }
    __builtin_amdgcn_s_setprio(0);
    // stage xv[it+1] into other buffer (no wait: prior reads retired before last barrier)
    if (it < 63) xvp += 2048;
    char* xvD = smem + 57344 + (((it + 1) & 1) << 15) + (w * 4) * 1024;
    #pragma unroll
    for (int j = 0; j < 4; ++j)
      gll16(xvp + (j >> 1) * 131072 + (j & 1) * 1024, xvD + j * 1024);
  }
  asm volatile("s_waitcnt vmcnt(0) lgkmcnt(0)" ::: "memory");
  __builtin_amdgcn_sched_barrier(0);
  __builtin_amdgcn_s_barrier();

  // ---- Epilogue: s^T = x - x_r^T into st[128][264] f16 ----
  _Float16* st = (_Float16*)smem;
  #pragma unroll
  for (int fm = 0; fm < 4; ++fm)
    #pragma unroll
    for (int fc = 0; fc < 4; ++fc) {
      int c = wb * 64 + fc * 16 + l15;
      int mb = wa * 64 + fm * 16 + l4 * 4;
      const float* xp = x + ((size_t)b * Cc + c) * Nn + m0 + mb;
      float4 v = *(const float4*)xp;
      float vv[4] = {v.x, v.y, v.z, v.w};
      #pragma unroll
      for (int i = 0; i < 4; ++i)
        st[(mb + i) * 264 + c] = (_Float16)(vv[i] - acc[fm][fc][i]);
    }
  __syncthreads();
  // ---- t = w_t . s + b_t, BN, ReLU, +x ; wave = o64(wb) x m64(wa) ----
  {
    const int ob = wb * 64, mh = wa * 64;
    f32x4 t[4][4];
    #pragma unroll
    for (int a = 0; a < 4; ++a)
      #pragma unroll
      for (int q = 0; q < 4; ++q) t[a][q] = fz4();
    #pragma unroll
    for (int kb = 0; kb < 8; ++kb) {
      half8 bfr[4];
      #pragma unroll
      for (int fm2 = 0; fm2 < 4; ++fm2)
        bfr[fm2] = *(const half8*)(st + (mh + fm2 * 16 + l15) * 264 + kb * 32 + l4 * 8);
      #pragma unroll
      for (int fo = 0; fo < 4; ++fo) {
        const int ot = (ob >> 4) + fo;
        half8 a = *(const half8*)((const char*)wtf + (ot * 8 + kb) * 1024 + lane * 16);
        #pragma unroll
        for (int fm2 = 0; fm2 < 4; ++fm2)
          t[fo][fm2] = mfma16(a, bfr[fm2], t[fo][fm2]);
      }
    }
    #pragma unroll
    for (int fo = 0; fo < 4; ++fo)
      #pragma unroll
      for (int i = 0; i < 4; ++i) {
        const int o = ob + fo * 16 + l4 * 4 + i;
        const float inv = gamma[o] * rsqrtf(rvar[o] + 1e-5f);
        const float addv = beta[o] - rmean[o] * inv;
        const float btv = bt[o];
        #pragma unroll
        for (int fm2 = 0; fm2 < 4; ++fm2) {
          const int m = m0 + mh + fm2 * 16 + l15;
          float tv = t[fo][fm2][i] + btv;
          float bn = tv * inv + addv;
          float xr = x[((size_t)b * Cc + o) * Nn + m];
          out[((size_t)b * Cc + o) * Nn + m] = xr + fmaxf(bn, 0.0f);
        }
      }
  }
}

extern "C" void kernel_launch(void* const* d_in, const int* in_sizes, int n_in,
                              void* d_out, int out_size, void* d_ws, size_t ws_size,
                              hipStream_t stream) {
  const float* x = (const float*)d_in[0];
  const float* wqk = (const float*)d_in[1];
  const float* wv = (const float*)d_in[2];
  const float* bv = (const float*)d_in[3];
  const float* wt = (const float*)d_in[4];
  const float* bt = (const float*)d_in[5];
  const float* gamma = (const float*)d_in[6];
  const float* beta = (const float*)d_in[7];
  const float* rmean = (const float*)d_in[8];
  const float* rvar = (const float*)d_in[9];
  float* out = (float*)d_out;

  char* ws = (char*)d_ws;
  size_t off = 0;
  auto alloc = [&](size_t nb) {
    char* p = ws + off;
    off += (nb + 255) & ~(size_t)255;
    return p;
  };
  _Float16* qkf = (_Float16*)alloc((size_t)Bb * Nn * C4 * 2);
  _Float16* xvf = (_Float16*)alloc((size_t)Bb * Cc * Nn * 2);
  float* stats = (float*)alloc((size_t)Bb * Nn * 4);
  _Float16* wqkh = (_Float16*)alloc((size_t)C4 * Cc * 2);
  _Float16* wqkl = (_Float16*)alloc((size_t)C4 * Cc * 2);
  _Float16* wvf = (_Float16*)alloc((size_t)Cc * Cc * 2);
  _Float16* wtf = (_Float16*)alloc((size_t)Cc * Cc * 2);

  k0_weights<<<dim3(256), dim3(256), 0, stream>>>(wqk, wv, wt, wqkh, wqkl, wvf, wtf);
  k23_qkv<<<dim3(512), dim3(512), 0, stream>>>(x, wqkh, wqkl, wvf, bv, qkf, xvf);
  k4_stats<<<dim3(512), dim3(512), 0, stream>>>(qkf, stats);
  k5_main<<<dim3(256), dim3(512), 0, stream>>>(x, qkf, xvf, stats, wtf, bt,
                                               gamma, beta, rmean, rvar, out);
}

// Round 10
// 140.174 us; speedup vs baseline: 1.9821x; 1.0646x over previous
//
#include <hip/hip_runtime.h>

#define Bb 8
#define Cc 256
#define C4 64
#define Nn 4096

typedef _Float16 half8 __attribute__((ext_vector_type(8)));
typedef float f32x4 __attribute__((ext_vector_type(4)));
typedef unsigned int u32;

__device__ __forceinline__ f32x4 fz4() {
  f32x4 z; z[0] = 0.f; z[1] = 0.f; z[2] = 0.f; z[3] = 0.f; return z;
}
__device__ __forceinline__ f32x4 mfma16(half8 a, half8 b, f32x4 c) {
  return __builtin_amdgcn_mfma_f32_16x16x32_f16(a, b, c, 0, 0, 0);
}
__device__ __forceinline__ u32 pkrtz(float a, float b) {
  typedef __fp16 h2n __attribute__((ext_vector_type(2)));
  h2n h = __builtin_amdgcn_cvt_pkrtz(a, b);
  return __builtin_bit_cast(u32, h);
}
__device__ __forceinline__ float ex2(float x) {
  float r;
  asm("v_exp_f32 %0, %1" : "=v"(r) : "v"(x));
  return r;
}

// Fragment-tiled f16 layout: tile = 16 rows x 32 k = 1KB, internally [(k>>3)&3][row&15][k&7].
// A/B-operand frag load = 64 lanes x 16B contiguous (byte = lane*16).

// ---------------- K0: weight prep -> fragment-tiled f16 (w_qk hi/lo, log2-scaled) ------
__global__ void k0_weights(const float* __restrict__ wqk, const float* __restrict__ wv,
                           const float* __restrict__ wt,
                           _Float16* __restrict__ wqkh, _Float16* __restrict__ wqkl,
                           _Float16* __restrict__ wvf, _Float16* __restrict__ wtf) {
  int idx = blockIdx.x * 256 + threadIdx.x;
  if (idx < C4 * Cc) {
    int o = idx >> 8, c = idx & 255;
    float f = wqk[idx] * 1.2011224087864498f;  // 1/sqrt(ln2): E' = E/ln2
    _Float16 h = (_Float16)f;
    int off = ((((o >> 4) * 8 + (c >> 5)) * 4 + ((c >> 3) & 3)) * 16 + (o & 15)) * 8 + (c & 7);
    wqkh[off] = h;
    wqkl[off] = (_Float16)(f - (float)h);
  }
  if (idx < Cc * Cc) {
    int o = idx >> 8, k = idx & 255;
    int off = ((((o >> 4) * 8 + (k >> 5)) * 4 + ((k >> 3) & 3)) * 16 + (o & 15)) * 8 + (k & 7);
    wvf[off] = (_Float16)wv[idx];
    wtf[off] = (_Float16)wt[idx];
  }
}

// ---------------- K23: qk + x_v, outputs fragment-tiled ----------------
__global__ __launch_bounds__(512) void k23_qkv(
    const float* __restrict__ x,
    const _Float16* __restrict__ wqkh, const _Float16* __restrict__ wqkl,
    const _Float16* __restrict__ wvf, const float* __restrict__ bv,
    _Float16* __restrict__ qkf, _Float16* __restrict__ xvf) {
  __shared__ _Float16 xh[64 * 264];  // [n][c] transposed x
  const int bid = blockIdx.x;
  const int b = bid & 7, n0 = (bid >> 3) * 64, tid = threadIdx.x;
  {
    const int cc = tid >> 3, nn = (tid & 7) * 8;
    #pragma unroll
    for (int ph = 0; ph < 4; ++ph) {
      int c = cc + ph * 64;
      const float* src = x + ((size_t)(b * Cc + c)) * Nn + n0 + nn;
      float4 v0 = *(const float4*)(src);
      float4 v1 = *(const float4*)(src + 4);
      float vv[8] = {v0.x, v0.y, v0.z, v0.w, v1.x, v1.y, v1.z, v1.w};
      #pragma unroll
      for (int j = 0; j < 8; ++j) xh[(nn + j) * 264 + c] = (_Float16)vv[j];
    }
  }
  __syncthreads();
  const int w = tid >> 6, lane = tid & 63, l15 = lane & 15, l4 = lane >> 4;
  {
    const int fn = w >> 1, ob = (w & 1) * 32;
    f32x4 acc[2] = {fz4(), fz4()};
    #pragma unroll
    for (int kb = 0; kb < 8; ++kb) {
      half8 ah = *(const half8*)(xh + (fn * 16 + l15) * 264 + kb * 32 + l4 * 8);
      #pragma unroll
      for (int f = 0; f < 2; ++f) {
        const int ot = (ob >> 4) + f;
        half8 bh = *(const half8*)((const char*)wqkh + (ot * 8 + kb) * 1024 + lane * 16);
        half8 bl = *(const half8*)((const char*)wqkl + (ot * 8 + kb) * 1024 + lane * 16);
        acc[f] = mfma16(ah, bh, acc[f]);
        acc[f] = mfma16(ah, bl, acc[f]);
      }
    }
    #pragma unroll
    for (int f = 0; f < 2; ++f)
      #pragma unroll
      for (int i = 0; i < 4; ++i) {
        const int n = n0 + fn * 16 + l4 * 4 + i;
        const int o = ob + f * 16 + l15;
        int off = ((((b * 256 + (n >> 4)) * 2 + (o >> 5)) * 4 + ((o >> 3) & 3)) * 16 +
                   (n & 15)) * 8 + (o & 7);
        qkf[off] = (_Float16)acc[f][i];
      }
  }
  {
    const int cb = w * 32;
    f32x4 acc[2][4];
    #pragma unroll
    for (int a = 0; a < 2; ++a)
      #pragma unroll
      for (int q = 0; q < 4; ++q) acc[a][q] = fz4();
    #pragma unroll
    for (int kb = 0; kb < 8; ++kb) {
      half8 bfr[4];
      #pragma unroll
      for (int fnb = 0; fnb < 4; ++fnb)
        bfr[fnb] = *(const half8*)(xh + (fnb * 16 + l15) * 264 + kb * 32 + l4 * 8);
      #pragma unroll
      for (int fc = 0; fc < 2; ++fc) {
        const int ct = (cb >> 4) + fc;
        half8 a = *(const half8*)((const char*)wvf + (ct * 8 + kb) * 1024 + lane * 16);
        #pragma unroll
        for (int fnb = 0; fnb < 4; ++fnb)
          acc[fc][fnb] = mfma16(a, bfr[fnb], acc[fc][fnb]);
      }
    }
    #pragma unroll
    for (int fc = 0; fc < 2; ++fc)
      #pragma unroll
      for (int fnb = 0; fnb < 4; ++fnb)
        #pragma unroll
        for (int i = 0; i < 4; ++i) {
          const int c = cb + fc * 16 + l4 * 4 + i;
          const int n = n0 + fnb * 16 + l15;
          int off = ((((b * 16 + (c >> 4)) * 128 + (n >> 5)) * 4 + ((n >> 3) & 3)) * 16 +
                     (c & 15)) * 8 + (n & 7);
          xvf[off] = (_Float16)(acc[fc][fnb][i] + bv[c]);
        }
  }
}

// ---------------- K4: softmax row stats  a'_n = 32 + log2(sum 2^(E'-32)) ----------------
__global__ __launch_bounds__(512, 4) void k4_stats(
    const _Float16* __restrict__ qkf, float* __restrict__ stats) {
  __shared__ float red[64][8];
  const int bid = blockIdx.x;
  const int b = bid & 7, n0 = (bid >> 3) * 64, tid = threadIdx.x;
  const int w = tid >> 6, lane = tid & 63, l15 = lane & 15, l4 = lane >> 4;
  const char* qbt = (const char*)qkf + (size_t)b * 524288;

  half8 qn_r[2][4];
  #pragma unroll
  for (int kb = 0; kb < 2; ++kb)
    #pragma unroll
    for (int fn = 0; fn < 4; ++fn)
      qn_r[kb][fn] = *(const half8*)(qbt + (((n0 >> 4) + fn) * 2 + kb) * 1024 + lane * 16);

  const char* qp = qbt + w * 2048 + lane * 16;
  half8 qa0 = *(const half8*)qp;
  half8 qa1 = *(const half8*)(qp + 1024);

  float sm[4] = {0.f, 0.f, 0.f, 0.f};
  for (int it = 0; it < 32; ++it) {
    f32x4 g[4] = {fz4(), fz4(), fz4(), fz4()};
    #pragma unroll
    for (int fn = 0; fn < 4; ++fn) g[fn] = mfma16(qa0, qn_r[0][fn], g[fn]);
    #pragma unroll
    for (int fn = 0; fn < 4; ++fn) g[fn] = mfma16(qa1, qn_r[1][fn], g[fn]);
    if (it < 31) qp += 16384;
    qa0 = *(const half8*)qp;
    qa1 = *(const half8*)(qp + 1024);
    #pragma unroll
    for (int fn = 0; fn < 4; ++fn)
      #pragma unroll
      for (int i = 0; i < 4; ++i)
        sm[fn] += ex2(g[fn][i] - 32.0f);
  }
  #pragma unroll
  for (int fn = 0; fn < 4; ++fn) {
    sm[fn] += __shfl_xor(sm[fn], 16, 64);
    sm[fn] += __shfl_xor(sm[fn], 32, 64);
  }
  if (l4 == 0) {
    #pragma unroll
    for (int fn = 0; fn < 4; ++fn) red[fn * 16 + l15][w] = sm[fn];
  }
  __syncthreads();
  if (tid < 64) {
    float t = 0.f;
    #pragma unroll
    for (int j = 0; j < 8; ++j) t += red[tid][j];
    stats[(size_t)b * Nn + n0 + tid] = 32.0f + log2f(t);
  }
}

// ---------------- K5: m128 x c256 tile; LDS = PT dbuf + an only ----------------
// ah/xb operands: register double-buffers loaded direct from L2 (coalesced 1KB frags),
// issued one full iteration ahead. Barrier = pure lgkmcnt PT handoff.
__global__ __launch_bounds__(512, 2) void k5_main(
    const float* __restrict__ x,
    const _Float16* __restrict__ qkf, const _Float16* __restrict__ xvf,
    const float* __restrict__ stats,
    const _Float16* __restrict__ wtf, const float* __restrict__ bt,
    const float* __restrict__ gamma, const float* __restrict__ beta,
    const float* __restrict__ rmean, const float* __restrict__ rvar,
    float* __restrict__ out) {
  // loop: an [0,16K) | PT0 [16K,32K) | PT1 [32K,48K).  epilogue: st[128][264] f16 (67.6K)
  __shared__ __align__(16) char smem[69632];
  const int bid = blockIdx.x;
  const int b = bid & 7, m0 = (bid >> 3) * 128, tid = threadIdx.x;
  const int w = tid >> 6, lane = tid & 63, l15 = lane & 15, l4 = lane >> 4;
  const int wa = w >> 2;  // m 64-half
  const int wb = w & 3;   // G: n16 quarter; PV: c64 quarter
  const size_t bq = (size_t)b * Nn;
  const char* qkt = (const char*)qkf + (size_t)b * 524288;
  const char* xvt = (const char*)xvf + (size_t)b * 2097152;
  const int key = l15 & 7;
  float* anL = (float*)smem;

  // stationary qm: B-operand frags for wave's m64 (4 m-tiles x 2 kb)
  half8 qm_r[2][4];
  #pragma unroll
  for (int kb = 0; kb < 2; ++kb)
    #pragma unroll
    for (int fm = 0; fm < 4; ++fm)
      qm_r[kb][fm] = *(const half8*)(qkt + ((((m0 >> 4) + wa * 4 + fm) * 2) + kb) * 1024 +
                                     lane * 16);

  // base pointers for per-iter coalesced frag loads
  const char* ah_base = qkt + (wb * 2) * 1024 + (size_t)lane * 16;        // +8192/iter, +1024/kb
  const char* xb_base = xvt + (size_t)(wb * 4) * 131072 + (size_t)lane * 16;  // +2048/iter

  f32x4 acc[4][4];
  #pragma unroll
  for (int a = 0; a < 4; ++a)
    #pragma unroll
    for (int q = 0; q < 4; ++q) acc[a][q] = fz4();

  // prologue: stage an (whole batch, 16KB), load ah[0]/xb[0] into A-buffers
  #pragma unroll
  for (int j = 0; j < 2; ++j)
    ((float4*)anL)[tid + 512 * j] = ((const float4*)(stats + bq))[tid + 512 * j];
  half8 ahA[2], ahB[2], xbA[4][2], xbB[4][2];
  #pragma unroll
  for (int kb = 0; kb < 2; ++kb) ahA[kb] = *(const half8*)(ah_base + kb * 1024);
  #pragma unroll
  for (int fc = 0; fc < 4; ++fc)
    #pragma unroll
    for (int kb = 0; kb < 2; ++kb)
      xbA[fc][kb] = *(const half8*)(xb_base + fc * 131072 + kb * 1024);
  __syncthreads();

#define K5_STEP(P, AH_CUR, AH_NXT, XB_CUR, XB_NXT)                                  \
  {                                                                                \
    const int it = it2 * 2 + (P);                                                  \
    /* issue next-iter operand loads (full-iteration latency cover) */             \
    {                                                                              \
      const char* ahs = ah_base + (size_t)(it + 1) * 8192;                         \
      _Pragma("unroll") for (int kb = 0; kb < 2; ++kb)                             \
          AH_NXT[kb] = *(const half8*)(ahs + kb * 1024);                           \
      const char* xbs = xb_base + (size_t)(it + 1) * 2048;                         \
      _Pragma("unroll") for (int fc = 0; fc < 4; ++fc)                             \
        _Pragma("unroll") for (int kb = 0; kb < 2; ++kb)                           \
            XB_NXT[fc][kb] = *(const half8*)(xbs + fc * 131072 + kb * 1024);       \
    }                                                                              \
    /* G: D[n16][m64] */                                                           \
    f32x4 g[4] = {fz4(), fz4(), fz4(), fz4()};                                     \
    _Pragma("unroll") for (int kb = 0; kb < 2; ++kb)                               \
      _Pragma("unroll") for (int fm = 0; fm < 4; ++fm)                             \
          g[fm] = mfma16(AH_CUR[kb], qm_r[kb][fm], g[fm]);                         \
    /* P = 2^(E' - a'_n) -> PT[m128][n64] swizzled */                              \
    char* PTp = smem + 16384 + ((P) << 14);                                        \
    {                                                                              \
      float4 an = *(const float4*)(anL + it * 64 + wb * 16 + l4 * 4);              \
      _Pragma("unroll") for (int fm = 0; fm < 4; ++fm) {                           \
        uint2 pk;                                                                  \
        pk.x = pkrtz(ex2(g[fm][0] - an.x), ex2(g[fm][1] - an.y));                  \
        pk.y = pkrtz(ex2(g[fm][2] - an.z), ex2(g[fm][3] - an.w));                  \
        *(uint2*)(PTp + (wa * 64 + fm * 16 + l15) * 128 +                          \
                  ((wb * 32 + l4 * 8) ^ (key << 4))) = pk;                         \
      }                                                                            \
    }                                                                              \
    /* barrier: PT handoff only */                                                 \
    asm volatile("s_waitcnt lgkmcnt(0)" ::: "memory");                             \
    __builtin_amdgcn_sched_barrier(0);                                             \
    __builtin_amdgcn_s_barrier();                                                  \
    /* PV: acc[m64][c64] += P[m][n] * xv[c][n] */                                  \
    __builtin_amdgcn_s_setprio(1);                                                 \
    _Pragma("unroll") for (int kb = 0; kb < 2; ++kb) {                             \
      half8 pa[4];                                                                 \
      _Pragma("unroll") for (int fm = 0; fm < 4; ++fm)                             \
          pa[fm] = *(const half8*)(PTp + (wa * 64 + fm * 16 + l15) * 128 +         \
                                   (((kb * 4 + l4) ^ key) * 16));                  \
      _Pragma("unroll") for (int fm = 0; fm < 4; ++fm)                             \
        _Pragma("unroll") for (int fc = 0; fc < 4; ++fc)                           \
            acc[fm][fc] = mfma16(pa[fm], XB_CUR[fc][kb], acc[fm][fc]);             \
    }                                                                              \
    __builtin_amdgcn_s_setprio(0);                                                 \
  }

  for (int it2 = 0; it2 < 32; ++it2) {
    K5_STEP(0, ahA, ahB, xbA, xbB)
    K5_STEP(1, ahB, ahA, xbB, xbA)
  }
#undef K5_STEP
  asm volatile("s_waitcnt lgkmcnt(0)" ::: "memory");
  __builtin_amdgcn_sched_barrier(0);
  __builtin_amdgcn_s_barrier();

  // ---- Epilogue: s^T = x - x_r^T into st[128][264] f16 ----
  _Float16* st = (_Float16*)smem;
  #pragma unroll
  for (int fm = 0; fm < 4; ++fm)
    #pragma unroll
    for (int fc = 0; fc < 4; ++fc) {
      int c = wb * 64 + fc * 16 + l15;
      int mb = wa * 64 + fm * 16 + l4 * 4;
      const float* xp = x + ((size_t)b * Cc + c) * Nn + m0 + mb;
      float4 v = *(const float4*)xp;
      float vv[4] = {v.x, v.y, v.z, v.w};
      #pragma unroll
      for (int i = 0; i < 4; ++i)
        st[(mb + i) * 264 + c] = (_Float16)(vv[i] - acc[fm][fc][i]);
    }
  __syncthreads();
  // ---- t = w_t . s + b_t, BN, ReLU, +x ; wave = o64(wb) x m64(wa) ----
  {
    const int ob = wb * 64, mh = wa * 64;
    f32x4 t[4][4];
    #pragma unroll
    for (int a = 0; a < 4; ++a)
      #pragma unroll
      for (int q = 0; q < 4; ++q) t[a][q] = fz4();
    #pragma unroll
    for (int kb = 0; kb < 8; ++kb) {
      half8 bfr[4];
      #pragma unroll
      for (int fm2 = 0; fm2 < 4; ++fm2)
        bfr[fm2] = *(const half8*)(st + (mh + fm2 * 16 + l15) * 264 + kb * 32 + l4 * 8);
      #pragma unroll
      for (int fo = 0; fo < 4; ++fo) {
        const int ot = (ob >> 4) + fo;
        half8 a = *(const half8*)((const char*)wtf + (ot * 8 + kb) * 1024 + lane * 16);
        #pragma unroll
        for (int fm2 = 0; fm2 < 4; ++fm2)
          t[fo][fm2] = mfma16(a, bfr[fm2], t[fo][fm2]);
      }
    }
    #pragma unroll
    for (int fo = 0; fo < 4; ++fo)
      #pragma unroll
      for (int i = 0; i < 4; ++i) {
        const int o = ob + fo * 16 + l4 * 4 + i;
        const float inv = gamma[o] * rsqrtf(rvar[o] + 1e-5f);
        const float addv = beta[o] - rmean[o] * inv;
        const float btv = bt[o];
        #pragma unroll
        for (int fm2 = 0; fm2 < 4; ++fm2) {
          const int m = m0 + mh + fm2 * 16 + l15;
          float tv = t[fo][fm2][i] + btv;
          float bn = tv * inv + addv;
          float xr = x[((size_t)b * Cc + o) * Nn + m];
          out[((size_t)b * Cc + o) * Nn + m] = xr + fmaxf(bn, 0.0f);
        }
      }
  }
}

extern "C" void kernel_launch(void* const* d_in, const int* in_sizes, int n_in,
                              void* d_out, int out_size, void* d_ws, size_t ws_size,
                              hipStream_t stream) {
  const float* x = (const float*)d_in[0];
  const float* wqk = (const float*)d_in[1];
  const float* wv = (const float*)d_in[2];
  const float* bv = (const float*)d_in[3];
  const float* wt = (const float*)d_in[4];
  const float* bt = (const float*)d_in[5];
  const float* gamma = (const float*)d_in[6];
  const float* beta = (const float*)d_in[7];
  const float* rmean = (const float*)d_in[8];
  const float* rvar = (const float*)d_in[9];
  float* out = (float*)d_out;

  char* ws = (char*)d_ws;
  size_t off = 0;
  auto alloc = [&](size_t nb) {
    char* p = ws + off;
    off += (nb + 255) & ~(size_t)255;
    return p;
  };
  _Float16* qkf = (_Float16*)alloc((size_t)Bb * Nn * C4 * 2);
  _Float16* xvf = (_Float16*)alloc((size_t)Bb * Cc * Nn * 2);
  float* stats = (float*)alloc((size_t)Bb * Nn * 4);
  _Float16* wqkh = (_Float16*)alloc((size_t)C4 * Cc * 2);
  _Float16* wqkl = (_Float16*)alloc((size_t)C4 * Cc * 2);
  _Float16* wvf = (_Float16*)alloc((size_t)Cc * Cc * 2);
  _Float16* wtf = (_Float16*)alloc((size_t)Cc * Cc * 2);

  k0_weights<<<dim3(256), dim3(256), 0, stream>>>(wqk, wv, wt, wqkh, wqkl, wvf, wtf);
  k23_qkv<<<dim3(512), dim3(512), 0, stream>>>(x, wqkh, wqkl, wvf, bv, qkf, xvf);
  k4_stats<<<dim3(512), dim3(512), 0, stream>>>(qkf, stats);
  k5_main<<<dim3(256), dim3(512), 0, stream>>>(x, qkf, xvf, stats, wtf, bt,
                                               gamma, beta, rmean, rvar, out);
}